// Round 12
// baseline (1439.621 us; speedup 1.0000x reference)
//
#include <hip/hip_runtime.h>
#include <hip/hip_bf16.h>

typedef __attribute__((ext_vector_type(8))) short short8;
typedef __attribute__((ext_vector_type(4))) float f32x4;

__device__ __forceinline__ unsigned short dev_f2bf(float f) {
  __hip_bfloat16 b = __float2bfloat16(f);
  union { __hip_bfloat16 b; unsigned short u; } c; c.b = b; return c.u;
}
__device__ __forceinline__ float dev_bf2f(unsigned short u) {
  union { unsigned int i; float f; } c; c.i = ((unsigned int)u) << 16; return c.f;
}

// async global->LDS, 16B per lane; dest = lds_base(wave-uniform) + lane*16
__device__ __forceinline__ void gload_lds16(const unsigned short* g, unsigned short* l) {
  __builtin_amdgcn_global_load_lds(
      (const __attribute__((address_space(1))) void*)(const void*)g,
      (__attribute__((address_space(3))) void*)(void*)l, 16, 0, 0);
}

struct GemmP {
  const unsigned short* A;   // bf16 bits
  const unsigned short* B;   // bf16 bits
  void* C;
  const float* biasN;        // bias by output col, may be null
  const float* biasM;        // bias by output row, may be null
  long long aHi, aLo, bHi, bLo, cHi, cLo;  // per-z base: (z>>4)*Hi + (z&15)*Lo
  int K;
  int sAm;                   // A row stride (k stride == 1)
  int sBn;                   // B row stride (k stride == 1)
  int sCm, sCn;
  float scale;
  int relu;
  int cdtype;                // 0=bf16, 1=f32, 3=f32 +=
};

// ---------------------------------------------------------------------------
// Big-GEMM: 256x256 tile, 512 threads (8 waves, 2Mx4N), BK=64, double-buffered
// LDS with counted vmcnt pipeline (never drains to 0 in main loop).
// LDS(row, c16) holds global(row, c16 ^ (row&7)); reads apply the same XOR.
// XCD swizzle (nwg%8==0): A-GROUPED decode: each XCD works a contiguous band
// of M with all N -> A panel L2-resident, minimizes FETCH.
// ---------------------------------------------------------------------------
__global__ __launch_bounds__(512, 2) void gemm256(GemmP p) {
  __shared__ __align__(16) unsigned short lds[2][2][256 * 64];  // 128 KiB

  const int tid = threadIdx.x;
  const int lane = tid & 63;
  const int wid = tid >> 6;       // 0..7
  const int wm = wid >> 2;        // 0..1
  const int wn = wid & 3;         // 0..3

  int id = blockIdx.y * gridDim.x + blockIdx.x;
  const int nwg = gridDim.x * gridDim.y;
  if ((nwg & 7) == 0) id = (id & 7) * (nwg >> 3) + (id >> 3);
  const long long m0 = (long long)(id / gridDim.y) * 256;   // A-grouped decode
  const long long n0 = (long long)(id % gridDim.y) * 256;

  const int srow8 = lane >> 3;                 // 0..7
  const int scol = ((lane & 7) ^ srow8) * 8;   // swizzled short offset

  f32x4 acc[8][4];
#pragma unroll
  for (int i = 0; i < 8; i++)
#pragma unroll
    for (int j = 0; j < 4; j++)
      acc[i][j] = f32x4{0.f, 0.f, 0.f, 0.f};

  const int nt = p.K >> 6;

  auto stage = [&](int buf, int t) {
    const long long k0 = (long long)t * 64;
#pragma unroll
    for (int h = 0; h < 4; h++)
      gload_lds16(p.A + (m0 + h * 64 + wid * 8 + srow8) * p.sAm + k0 + scol,
                  &lds[buf][0][(h * 64 + wid * 8) * 64]);
#pragma unroll
    for (int h = 0; h < 4; h++)
      gload_lds16(p.B + (n0 + h * 64 + wid * 8 + srow8) * p.sBn + k0 + scol,
                  &lds[buf][1][(h * 64 + wid * 8) * 64]);
  };

  stage(0, 0);
  stage(1, 1);

  for (int t = 0; t < nt; t++) {
    const int cur = t & 1;
    if (t + 1 < nt) asm volatile("s_waitcnt vmcnt(8)" ::: "memory");
    else            asm volatile("s_waitcnt vmcnt(0)" ::: "memory");
    __builtin_amdgcn_s_barrier();
    __builtin_amdgcn_sched_barrier(0);

    const unsigned short* Asb = lds[cur][0];
    const unsigned short* Bsb = lds[cur][1];
#pragma unroll
    for (int ks = 0; ks < 2; ks++) {
      const int c16 = ks * 4 + (lane >> 4);
      short8 a[8], b[4];
#pragma unroll
      for (int i = 0; i < 8; i++) {
        const int r = wm * 128 + i * 16 + (lane & 15);
        a[i] = *(const short8*)&Asb[r * 64 + ((c16 ^ (r & 7)) << 3)];
      }
#pragma unroll
      for (int j = 0; j < 4; j++) {
        const int r = wn * 64 + j * 16 + (lane & 15);
        b[j] = *(const short8*)&Bsb[r * 64 + ((c16 ^ (r & 7)) << 3)];
      }
      __builtin_amdgcn_s_setprio(1);
#pragma unroll
      for (int i = 0; i < 8; i++)
#pragma unroll
        for (int j = 0; j < 4; j++)
          acc[i][j] = __builtin_amdgcn_mfma_f32_16x16x32_bf16(a[i], b[j], acc[i][j], 0, 0, 0);
      __builtin_amdgcn_s_setprio(0);
    }
    __builtin_amdgcn_sched_barrier(0);
    __builtin_amdgcn_s_barrier();
    __builtin_amdgcn_sched_barrier(0);
    if (t + 2 < nt) stage(cur, t + 2);
  }

#pragma unroll
  for (int i = 0; i < 8; i++) {
#pragma unroll
    for (int j = 0; j < 4; j++) {
      const int col = (int)n0 + wn * 64 + j * 16 + (lane & 15);
      float bn = p.biasN ? p.biasN[col] : 0.f;
#pragma unroll
      for (int r = 0; r < 4; r++) {
        const long long row = m0 + wm * 128 + i * 16 + ((lane >> 4) << 2) + r;
        float v = acc[i][j][r] * p.scale + bn;
        if (p.relu) v = fmaxf(v, 0.f);
        const long long addr = row * p.sCm + col;
        if (p.cdtype == 0)      ((unsigned short*)p.C)[addr] = dev_f2bf(v);
        else if (p.cdtype == 3) ((float*)p.C)[addr] += v;
        else                    ((float*)p.C)[addr] = v;
      }
    }
  }
}

// ---------------------------------------------------------------------------
// Fully fused attention, QBLK=64: per block = 64 q-rows x one head z.
// LDS: u0 = [As 8KB | Bs 32KB] (Ps 32KB aliases u0 after phase 1), Vs 32KB.
// Total 73 KB -> 2 blocks/CU. Phases: QK^T -> in-reg softmax -> Ps(bf16,
// granule-XOR) -> PV -> bf16 store in place over the Q slice.
// ---------------------------------------------------------------------------
__global__ __launch_bounds__(256, 2) void attn_kernel(
    const unsigned short* __restrict__ Q, const unsigned short* __restrict__ EK,
    const unsigned short* __restrict__ EVt) {
  __shared__ __align__(16) unsigned short u0[20480];       // As(4096) + Bs(16384)
  __shared__ __align__(16) unsigned short Vs[64 * 256];    // 32 KB
  __shared__ float red[2][2][64];

  unsigned short* As = u0;           // 64 x 64
  unsigned short* Bs = u0 + 4096;    // 256 x 64
  unsigned short* Ps = u0;           // 64 x 256 (aliases As+Bs after QK phase)

  const int tid = threadIdx.x;
  const int lane = tid & 63;
  const int wid = tid >> 6;
  const int wm = wid >> 1, wn = wid & 1;   // 2x2 wave grid
  const int m0 = blockIdx.x * 64;
  const int z = blockIdx.z;
  unsigned short* Qz = (unsigned short*)Q + (long long)(z >> 4) * 4194304 + (long long)(z & 15) * 64;
  const unsigned short* EKz = EK + (long long)z * 16384;
  const unsigned short* EVz = EVt + (long long)z * 16384;

  const int srow = tid >> 3;
  const int scol = ((tid & 7) ^ (srow & 7)) * 8;

#pragma unroll
  for (int i = 0; i < 2; i++)
    gload_lds16(Qz + (long long)(m0 + i * 32 + srow) * 1024 + scol, &As[i * 2048 + wid * 512]);
#pragma unroll
  for (int i = 0; i < 8; i++)
    gload_lds16(EKz + (long long)(i * 32 + srow) * 64 + scol, &Bs[i * 2048 + wid * 512]);
  // EVt: physical granule pg holds logical granule (pg&31)^(d&7) of row d=pg>>5
#pragma unroll
  for (int c = 0; c < 8; c++) {
    const int pg = (c * 4 + wid) * 64 + lane;
    const int d = pg >> 5, gp = pg & 31;
    gload_lds16(EVz + d * 256 + ((gp ^ (d & 7)) << 3), &Vs[(c * 4 + wid) * 512]);
  }
  __syncthreads();

  f32x4 acc[2][8];
#pragma unroll
  for (int i = 0; i < 2; i++)
#pragma unroll
    for (int j = 0; j < 8; j++)
      acc[i][j] = f32x4{0.f, 0.f, 0.f, 0.f};

#pragma unroll
  for (int ks = 0; ks < 2; ks++) {
    const int c16 = ks * 4 + (lane >> 4);
    short8 a[2], b[8];
#pragma unroll
    for (int i = 0; i < 2; i++) {
      const int row = wm * 32 + i * 16 + (lane & 15);
      a[i] = *(const short8*)&As[row * 64 + ((c16 ^ (row & 7)) << 3)];
    }
#pragma unroll
    for (int j = 0; j < 8; j++) {
      const int row = wn * 128 + j * 16 + (lane & 15);
      b[j] = *(const short8*)&Bs[row * 64 + ((c16 ^ (row & 7)) << 3)];
    }
#pragma unroll
    for (int i = 0; i < 2; i++)
#pragma unroll
      for (int j = 0; j < 8; j++)
        acc[i][j] = __builtin_amdgcn_mfma_f32_16x16x32_bf16(a[i], b[j], acc[i][j], 0, 0, 0);
  }

  const int rr4 = (lane >> 4) << 2;
#pragma unroll
  for (int i = 0; i < 2; i++) {
#pragma unroll
    for (int r = 0; r < 4; r++) {
      float m = acc[i][0][r];
#pragma unroll
      for (int j = 1; j < 8; j++) m = fmaxf(m, acc[i][j][r]);
      m = fmaxf(m, __shfl_xor(m, 1));
      m = fmaxf(m, __shfl_xor(m, 2));
      m = fmaxf(m, __shfl_xor(m, 4));
      m = fmaxf(m, __shfl_xor(m, 8));
      if ((lane & 15) == 0) red[0][wn][wm * 32 + i * 16 + rr4 + r] = m;
    }
  }
  __syncthreads();
  float fm[2][4];
#pragma unroll
  for (int i = 0; i < 2; i++)
#pragma unroll
    for (int r = 0; r < 4; r++) {
      const int row = wm * 32 + i * 16 + rr4 + r;
      fm[i][r] = fmaxf(red[0][0][row], red[0][1][row]);
    }
#pragma unroll
  for (int i = 0; i < 2; i++) {
#pragma unroll
    for (int r = 0; r < 4; r++) {
      float s = 0.f;
#pragma unroll
      for (int j = 0; j < 8; j++) {
        float e = __expf((acc[i][j][r] - fm[i][r]) * 0.125f);
        acc[i][j][r] = e;
        s += e;
      }
      s += __shfl_xor(s, 1);
      s += __shfl_xor(s, 2);
      s += __shfl_xor(s, 4);
      s += __shfl_xor(s, 8);
      if ((lane & 15) == 0) red[1][wn][wm * 32 + i * 16 + rr4 + r] = s;
    }
  }
  __syncthreads();   // last As/Bs reads done; Ps may now overwrite u0
#pragma unroll
  for (int i = 0; i < 2; i++) {
#pragma unroll
    for (int r = 0; r < 4; r++) {
      const int row = wm * 32 + i * 16 + rr4 + r;
      const float inv = 1.f / (red[1][0][row] + red[1][1][row]);
#pragma unroll
      for (int j = 0; j < 8; j++) {
        const int col = wn * 128 + j * 16 + (lane & 15);
        Ps[row * 256 + (((col >> 3) ^ (row & 7)) << 3) + (col & 7)] =
            dev_f2bf(acc[i][j][r] * inv);
      }
    }
  }
  __syncthreads();

  // PV: out[q][d] = sum_k P[q,k] * EVt[d,k]; per wave 32q x 32d
  f32x4 acc2[2][2];
#pragma unroll
  for (int i = 0; i < 2; i++)
#pragma unroll
    for (int jj = 0; jj < 2; jj++)
      acc2[i][jj] = f32x4{0.f, 0.f, 0.f, 0.f};

#pragma unroll
  for (int ks = 0; ks < 8; ks++) {
    const int G = ks * 4 + (lane >> 4);
    short8 pa[2], pb[2];
#pragma unroll
    for (int i = 0; i < 2; i++) {
      const int row = wm * 32 + i * 16 + (lane & 15);
      pa[i] = *(const short8*)&Ps[row * 256 + ((G ^ (row & 7)) << 3)];
    }
#pragma unroll
    for (int jj = 0; jj < 2; jj++) {
      const int d = wn * 32 + jj * 16 + (lane & 15);
      pb[jj] = *(const short8*)&Vs[d * 256 + ((G ^ (d & 7)) << 3)];
    }
#pragma unroll
    for (int i = 0; i < 2; i++)
#pragma unroll
      for (int jj = 0; jj < 2; jj++)
        acc2[i][jj] = __builtin_amdgcn_mfma_f32_16x16x32_bf16(pa[i], pb[jj], acc2[i][jj], 0, 0, 0);
  }

#pragma unroll
  for (int i = 0; i < 2; i++) {
#pragma unroll
    for (int jj = 0; jj < 2; jj++) {
#pragma unroll
      for (int r = 0; r < 4; r++) {
        const int qrow = m0 + wm * 32 + i * 16 + rr4 + r;
        const int dcol = wn * 32 + jj * 16 + (lane & 15);
        Qz[(long long)qrow * 1024 + dcol] = dev_f2bf(acc2[i][jj][r]);
      }
    }
  }
}

// General NT GEMM (small/batched shapes): C[z,m,n] = scale*sum_k A[m,k]*B[n,k]
template<int BM, int BN, int WM, int WN>
__global__ __launch_bounds__(256, 2) void gemm_nt(GemmP p) {
  constexpr int BK = 64;
  constexpr int TM = BM / WM, TN = BN / WN;
  constexpr int FM = TM / 16, FN = TN / 16;
  __shared__ __align__(16) unsigned short As[BM * BK];
  __shared__ __align__(16) unsigned short Bs[BN * BK];

  const int tid = threadIdx.x;
  const int lane = tid & 63;
  const int wid = tid >> 6;
  const int wm = wid / WN, wn = wid % WN;
  const int m0 = blockIdx.x * BM;
  const int n0 = blockIdx.y * BN;
  const int z = blockIdx.z;
  const int zq = z >> 4, zr = z & 15;
  const unsigned short* Ag = p.A + (long long)zq * p.aHi + (long long)zr * p.aLo;
  const unsigned short* Bg = p.B + (long long)zq * p.bHi + (long long)zr * p.bLo;

  const int srow = tid >> 3;                      // 0..31
  const int scol = ((tid & 7) ^ (srow & 7)) * 8;  // swizzled 16B column
  constexpr int AC = BM / 32, BC = BN / 32;

  f32x4 acc[FM][FN];
#pragma unroll
  for (int i = 0; i < FM; i++)
#pragma unroll
    for (int j = 0; j < FN; j++)
      acc[i][j] = f32x4{0.f, 0.f, 0.f, 0.f};

  for (int k0 = 0; k0 < p.K; k0 += BK) {
#pragma unroll
    for (int i = 0; i < AC; i++)
      gload_lds16(Ag + (long long)(m0 + i * 32 + srow) * p.sAm + (k0 + scol),
                  &As[i * 2048 + wid * 512]);
#pragma unroll
    for (int i = 0; i < BC; i++)
      gload_lds16(Bg + (long long)(n0 + i * 32 + srow) * p.sBn + (k0 + scol),
                  &Bs[i * 2048 + wid * 512]);
    __syncthreads();
#pragma unroll
    for (int ks = 0; ks < 2; ks++) {
      const int c16 = ks * 4 + (lane >> 4);
      short8 a[FM], b[FN];
#pragma unroll
      for (int i = 0; i < FM; i++) {
        const int row = wm * TM + i * 16 + (lane & 15);
        a[i] = *(const short8*)&As[row * 64 + ((c16 ^ (row & 7)) << 3)];
      }
#pragma unroll
      for (int j = 0; j < FN; j++) {
        const int row = wn * TN + j * 16 + (lane & 15);
        b[j] = *(const short8*)&Bs[row * 64 + ((c16 ^ (row & 7)) << 3)];
      }
#pragma unroll
      for (int i = 0; i < FM; i++)
#pragma unroll
        for (int j = 0; j < FN; j++)
          acc[i][j] = __builtin_amdgcn_mfma_f32_16x16x32_bf16(a[i], b[j], acc[i][j], 0, 0, 0);
    }
    __syncthreads();
  }

  const long long zc_ = (long long)zq * p.cHi + (long long)zr * p.cLo;
#pragma unroll
  for (int i = 0; i < FM; i++) {
#pragma unroll
    for (int j = 0; j < FN; j++) {
      const int col = n0 + wn * TN + j * 16 + (lane & 15);
      float bn = p.biasN ? p.biasN[col] : 0.f;
#pragma unroll
      for (int r = 0; r < 4; r++) {
        const int row = m0 + wm * TM + i * 16 + ((lane >> 4) << 2) + r;
        float v = acc[i][j][r] * p.scale + bn;
        if (p.biasM) v += p.biasM[row];
        if (p.relu) v = fmaxf(v, 0.f);
        const long long addr = zc_ + (long long)row * p.sCm + (long long)col * p.sCn;
        if (p.cdtype == 0)      ((unsigned short*)p.C)[addr] = dev_f2bf(v);
        else if (p.cdtype == 3) ((float*)p.C)[addr] += v;
        else                    ((float*)p.C)[addr] = v;
      }
    }
  }
}

// 64x64 tiled transpose: in [b][4096][1024] -> out [b][1024][4096] (bf16)
__global__ __launch_bounds__(256) void transpose_kernel(const unsigned short* __restrict__ in,
                                                        unsigned short* __restrict__ out) {
  __shared__ unsigned short t[64][72];
  const int b = blockIdx.z;
  const int n0 = blockIdx.x * 64, c0 = blockIdx.y * 64;
  const int r = threadIdx.x >> 2;          // 0..63
  const int cc = (threadIdx.x & 3) * 16;   // 0,16,32,48
  const unsigned short* ip = in + (size_t)b * 4194304 + (size_t)n0 * 1024 + c0;
  *(short8*)&t[r][cc]     = *(const short8*)(ip + (size_t)r * 1024 + cc);
  *(short8*)&t[r][cc + 8] = *(const short8*)(ip + (size_t)r * 1024 + cc + 8);
  __syncthreads();
  unsigned short* op = out + (size_t)b * 4194304 + (size_t)c0 * 4096 + n0;
  short8 w0, w1;
#pragma unroll
  for (int j = 0; j < 8; j++) {
    w0[j] = (short)t[cc + j][r];
    w1[j] = (short)t[cc + 8 + j][r];
  }
  *(short8*)(op + (size_t)r * 4096 + cc)     = w0;
  *(short8*)(op + (size_t)r * 4096 + cc + 8) = w1;
}

// f32 -> bf16, x4 vectorized, grid-stride
__global__ void cvt_kernel(const float* __restrict__ src, unsigned short* __restrict__ dst,
                           long long n4) {
  long long i = (long long)blockIdx.x * blockDim.x + threadIdx.x;
  const long long stride = (long long)gridDim.x * blockDim.x;
  for (; i < n4; i += stride) {
    float4 v = ((const float4*)src)[i];
    ushort4 u;
    u.x = dev_f2bf(v.x); u.y = dev_f2bf(v.y); u.z = dev_f2bf(v.z); u.w = dev_f2bf(v.w);
    ((ushort4*)dst)[i] = u;
  }
}

// LN over rows of 1024: t = bf2f(xr) + bf2f(yr) (f32 math in-register).
// Writes bf16 LN(t) to xw (if non-null) and f32 LN(t) to fout (if non-null).
__global__ __launch_bounds__(256) void add_ln_kernel(
    const unsigned short* __restrict__ xr, const unsigned short* __restrict__ yr,
    unsigned short* __restrict__ xw, float* __restrict__ fout,
    const float* __restrict__ g, const float* __restrict__ b) {
  const long long row = blockIdx.x;
  const int tid = threadIdx.x;
  ushort4 xv = ((const ushort4*)(xr + row * 1024))[tid];
  ushort4 yv = ((const ushort4*)(yr + row * 1024))[tid];
  float4 t = {dev_bf2f(xv.x) + dev_bf2f(yv.x), dev_bf2f(xv.y) + dev_bf2f(yv.y),
              dev_bf2f(xv.z) + dev_bf2f(yv.z), dev_bf2f(xv.w) + dev_bf2f(yv.w)};
  float s = t.x + t.y + t.z + t.w;
  float ss = t.x * t.x + t.y * t.y + t.z * t.z + t.w * t.w;
#pragma unroll
  for (int off = 32; off > 0; off >>= 1) { s += __shfl_xor(s, off); ss += __shfl_xor(ss, off); }
  __shared__ float sm[8];
  const int wid = tid >> 6, lane = tid & 63;
  if (lane == 0) { sm[wid] = s; sm[4 + wid] = ss; }
  __syncthreads();
  s = sm[0] + sm[1] + sm[2] + sm[3];
  ss = sm[4] + sm[5] + sm[6] + sm[7];
  const float mean = s * (1.f / 1024.f);
  const float var = ss * (1.f / 1024.f) - mean * mean;
  const float rs = rsqrtf(var + 1e-5f);
  float4 gv = ((const float4*)g)[tid];
  float4 bv = ((const float4*)b)[tid];
  float4 o = {(t.x - mean) * rs * gv.x + bv.x, (t.y - mean) * rs * gv.y + bv.y,
              (t.z - mean) * rs * gv.z + bv.z, (t.w - mean) * rs * gv.w + bv.w};
  if (xw) {
    ushort4 ob;
    ob.x = dev_f2bf(o.x); ob.y = dev_f2bf(o.y); ob.z = dev_f2bf(o.z); ob.w = dev_f2bf(o.w);
    ((ushort4*)(xw + row * 1024))[tid] = ob;
  }
  if (fout) ((float4*)(fout + row * 1024))[tid] = o;
}

// canary: unambiguous "workspace too small" signal (absmax ~ 100+max|ref|)
__global__ void fill_canary_kernel(float* p, long long n) {
  long long i = (long long)blockIdx.x * blockDim.x + threadIdx.x;
  const long long stride = (long long)gridDim.x * blockDim.x;
  for (; i < n; i += stride) p[i] = 100.0f;
}

extern "C" void kernel_launch(void* const* d_in, const int* in_sizes, int n_in,
                              void* d_out, int out_size, void* d_ws, size_t ws_size,
                              hipStream_t stream) {
  const float* x_in  = (const float*)d_in[0];
  const float* E_w   = (const float*)d_in[1];
  const float* E_b   = (const float*)d_in[2];
  const float* Wq    = (const float*)d_in[3];
  const float* Wk    = (const float*)d_in[4];
  const float* Wv    = (const float*)d_in[5];
  const float* wo_w  = (const float*)d_in[6];
  const float* wo_b  = (const float*)d_in[7];
  const float* ln1_g = (const float*)d_in[8];
  const float* ln1_b = (const float*)d_in[9];
  const float* ff_w1 = (const float*)d_in[10];
  const float* ff_b1 = (const float*)d_in[11];
  const float* ff_w2 = (const float*)d_in[12];
  const float* ff_b2 = (const float*)d_in[13];
  const float* ln2_g = (const float*)d_in[14];
  const float* ln2_b = (const float*)d_in[15];

  float* xfout = (float*)d_out;   // final f32 output (written only by last LN)

  char* ws = (char*)d_ws;
  size_t off = 0;
  auto alloc = [&](size_t bytes) -> char* {
    char* p = ws + off;
    off = (off + bytes + 255) & ~(size_t)255;
    return p;
  };
  unsigned short* E16 = (unsigned short*)alloc(1048576ULL * 2);  // E_w bf16 [256,4096]
  unsigned short* Wq16 = (unsigned short*)alloc(2097152ULL * 2); // both layers
  unsigned short* Wk16 = (unsigned short*)alloc(2097152ULL * 2);
  unsigned short* Wv16 = (unsigned short*)alloc(2097152ULL * 2);
  unsigned short* Wo16 = (unsigned short*)alloc(2097152ULL * 2);
  unsigned short* F116 = (unsigned short*)alloc(8388608ULL * 2);
  unsigned short* F216 = (unsigned short*)alloc(8388608ULL * 2);
  unsigned short* xE  = (unsigned short*)alloc(1048576ULL * 2);  // [b][256][1024]
  unsigned short* EK  = (unsigned short*)alloc(1048576ULL * 2);  // [z][256][64]
  unsigned short* EVt = (unsigned short*)alloc(1048576ULL * 2);  // [z][64][256]
  unsigned short* xd  = (unsigned short*)alloc(16777216ULL * 2); // bf16 residual x
  unsigned short* xT  = (unsigned short*)alloc(16777216ULL * 2); // x^T; later Q/cat
  unsigned short* Qb4 = xT;   // alias: xT dead once pe is done; Q/cat [16384][1024]
  unsigned short* ybuf = (unsigned short*)alloc(16777216ULL * 2); // bf16 y (attn/ffn out)

  size_t rem = (ws_size > off) ? ws_size - off : 0;
  size_t Rbytes = rem > 512 ? rem - 512 : 0;
  if (Rbytes > 134217728ULL) Rbytes = 134217728ULL;
  int rowc = 16384;
  while (rowc > 256 && (size_t)rowc * 8192ULL > Rbytes) rowc >>= 1;
  if ((size_t)rowc * 8192ULL > Rbytes) {
    fill_canary_kernel<<<2048, 256, 0, stream>>>(xfout, (long long)out_size);
    return;
  }
  char* R = alloc(Rbytes);   // h buffer region

  auto cvt = [&](const float* s, unsigned short* d, long long n) {
    long long n4 = n / 4;
    int grid = (int)((n4 + 255) / 256);
    if (grid > 4096) grid = 4096;
    cvt_kernel<<<grid, 256, 0, stream>>>(s, d, n4);
  };

  // ---- all conversions once
  cvt(x_in, xd, 16777216);
  cvt(E_w, E16, 1048576);
  cvt(Wq, Wq16, 2097152);
  cvt(Wk, Wk16, 2097152);
  cvt(Wv, Wv16, 2097152);
  cvt(wo_w, Wo16, 2097152);
  cvt(ff_w1, F116, 8388608);
  cvt(ff_w2, F216, 8388608);

  for (int l = 0; l < 2; l++) {
    const unsigned short* WqL = Wq16 + (size_t)l * 1048576;
    const unsigned short* WkL = Wk16 + (size_t)l * 1048576;
    const unsigned short* WvL = Wv16 + (size_t)l * 1048576;
    const unsigned short* WoL = Wo16 + (size_t)l * 1048576;
    const unsigned short* F1L = F116 + (size_t)l * 4194304;
    const unsigned short* F2L = F216 + (size_t)l * 4194304;

    // ---- xT[b][c][n] = x[b][n][c]
    transpose_kernel<<<dim3(64, 16, 4), 256, 0, stream>>>(xd, xT);

    // ---- xE[b][k][c] = sum_n E_w[k,n] * xT[b][c][n]   (pure NT, z = b)
    GemmP pe{};
    pe.A = E16; pe.sAm = 4096; pe.K = 4096;
    pe.B = xT; pe.sBn = 4096; pe.bLo = 4194304;
    pe.C = xE; pe.cLo = 262144; pe.sCm = 1024; pe.sCn = 1;
    pe.scale = 1.f; pe.cdtype = 0;
    gemm_nt<64,64,2,2><<<dim3(4, 16, 4), 256, 0, stream>>>(pe);

    // ---- EK[z][k][d] = xE[b] @ Wk[h]^T + E_b[k]   (z = b*16+h)
    GemmP pk{};
    pk.A = xE; pk.sAm = 1024; pk.K = 1024; pk.aHi = 262144; pk.aLo = 0;
    pk.B = WkL; pk.sBn = 1024; pk.bHi = 0; pk.bLo = 65536;
    pk.C = EK; pk.cHi = 262144; pk.cLo = 16384; pk.sCm = 64; pk.sCn = 1;
    pk.biasM = E_b; pk.scale = 1.f; pk.cdtype = 0;
    gemm_nt<64,64,2,2><<<dim3(4, 1, 64), 256, 0, stream>>>(pk);
    // ---- EVt[z][d][k] = (xE[b] @ Wv[h]^T + E_b[k])^T
    GemmP pv2 = pk;
    pv2.B = WvL; pv2.C = EVt; pv2.sCm = 1; pv2.sCn = 256;
    gemm_nt<64,64,2,2><<<dim3(4, 1, 64), 256, 0, stream>>>(pv2);

    // ---- Q (all batches) = x @ Wq^T : [16384,1024]   (overwrites xT region)
    GemmP pq{};
    pq.A = xd; pq.sAm = 1024; pq.K = 1024;
    pq.B = WqL; pq.sBn = 1024;
    pq.C = Qb4; pq.sCm = 1024; pq.sCn = 1;
    pq.scale = 1.f; pq.cdtype = 0;
    gemm256<<<dim3(64, 4, 1), 512, 0, stream>>>(pq);

    // ---- fused attention: cat[b][n][h*64+d] overwrites Q slice in place
    attn_kernel<<<dim3(64, 1, 64), 256, 0, stream>>>(Qb4, EK, EVt);

    // ---- y = cat @ wo^T + wo_b -> bf16 ybuf
    GemmP pw{};
    pw.A = Qb4; pw.sAm = 1024; pw.K = 1024;
    pw.B = WoL; pw.sBn = 1024;
    pw.biasN = wo_b + (size_t)l * 1024;
    pw.C = ybuf; pw.cdtype = 0;
    pw.sCm = 1024; pw.sCn = 1; pw.scale = 1.f;
    gemm256<<<dim3(64, 4, 1), 512, 0, stream>>>(pw);

    // ---- x = LN1(x + y)  (bf16 in, bf16 out)
    add_ln_kernel<<<16384, 256, 0, stream>>>(xd, ybuf, xd, nullptr,
                                             ln1_g + (size_t)l * 1024,
                                             ln1_b + (size_t)l * 1024);

    // ---- FFN, row-chunked: h = relu(x@W1^T+b1) -> R; y = h@W2^T+b2 -> ybuf
    for (int r0 = 0; r0 < 16384; r0 += rowc) {
      GemmP f1{};
      f1.A = xd + (size_t)r0 * 1024; f1.sAm = 1024; f1.K = 1024;
      f1.B = F1L; f1.sBn = 1024;
      f1.C = R; f1.sCm = 4096; f1.sCn = 1;
      f1.biasN = ff_b1 + (size_t)l * 4096; f1.scale = 1.f; f1.relu = 1; f1.cdtype = 0;
      gemm256<<<dim3(rowc / 256, 16, 1), 512, 0, stream>>>(f1);

      GemmP f2{};
      f2.A = (unsigned short*)R; f2.sAm = 4096; f2.K = 4096;
      f2.B = F2L; f2.sBn = 4096;
      f2.biasN = ff_b2 + (size_t)l * 1024;
      f2.C = ybuf + (size_t)r0 * 1024; f2.cdtype = 0;
      f2.sCm = 1024; f2.sCn = 1; f2.scale = 1.f;
      gemm256<<<dim3(rowc / 256, 4, 1), 512, 0, stream>>>(f2);
    }
    // ---- x = LN2(x + y); final layer writes f32 straight to d_out
    if (l == 1)
      add_ln_kernel<<<16384, 256, 0, stream>>>(xd, ybuf, nullptr, xfout,
                                               ln2_g + 1024, ln2_b + 1024);
    else
      add_ln_kernel<<<16384, 256, 0, stream>>>(xd, ybuf, xd, nullptr,
                                               ln2_g, ln2_b);
  }
}

// Round 13
// 1264.783 us; speedup vs baseline: 1.1382x; 1.1382x over previous
//
#include <hip/hip_runtime.h>
#include <hip/hip_bf16.h>

typedef __attribute__((ext_vector_type(8))) short short8;
typedef __attribute__((ext_vector_type(4))) float f32x4;

__device__ __forceinline__ unsigned short dev_f2bf(float f) {
  __hip_bfloat16 b = __float2bfloat16(f);
  union { __hip_bfloat16 b; unsigned short u; } c; c.b = b; return c.u;
}
__device__ __forceinline__ float dev_bf2f(unsigned short u) {
  union { unsigned int i; float f; } c; c.i = ((unsigned int)u) << 16; return c.f;
}

// async global->LDS, 16B per lane; dest = lds_base(wave-uniform) + lane*16
__device__ __forceinline__ void gload_lds16(const unsigned short* g, unsigned short* l) {
  __builtin_amdgcn_global_load_lds(
      (const __attribute__((address_space(1))) void*)(const void*)g,
      (__attribute__((address_space(3))) void*)(void*)l, 16, 0, 0);
}

struct GemmP {
  const unsigned short* A;   // bf16 bits
  const unsigned short* B;   // bf16 bits
  void* C;
  const float* biasN;        // bias by output col, may be null
  const float* biasM;        // bias by output row, may be null
  long long aHi, aLo, bHi, bLo, cHi, cLo;  // per-z base: (z>>4)*Hi + (z&15)*Lo
  int K;
  int sAm;                   // A row stride (k stride == 1)
  int sBn;                   // B row stride (k stride == 1)
  int sCm, sCn;
  float scale;
  int relu;
  int cdtype;                // 0=bf16, 1=f32, 3=f32 +=
};

// ---------------------------------------------------------------------------
// Big-GEMM: 256x256 tile, 512 threads (8 waves, 2Mx4N), BK=64, double-buffered
// LDS with counted vmcnt pipeline (never drains to 0 in main loop).
// LDS(row, c16) holds global(row, c16 ^ (row&7)); reads apply the same XOR.
// XCD swizzle (nwg%8==0): A-GROUPED decode: each XCD works a contiguous band
// of M with all N -> A panel L2-resident, minimizes FETCH.
// ---------------------------------------------------------------------------
__global__ __launch_bounds__(512, 2) void gemm256(GemmP p) {
  __shared__ __align__(16) unsigned short lds[2][2][256 * 64];  // 128 KiB

  const int tid = threadIdx.x;
  const int lane = tid & 63;
  const int wid = tid >> 6;       // 0..7
  const int wm = wid >> 2;        // 0..1
  const int wn = wid & 3;         // 0..3

  int id = blockIdx.y * gridDim.x + blockIdx.x;
  const int nwg = gridDim.x * gridDim.y;
  if ((nwg & 7) == 0) id = (id & 7) * (nwg >> 3) + (id >> 3);
  const long long m0 = (long long)(id / gridDim.y) * 256;   // A-grouped decode
  const long long n0 = (long long)(id % gridDim.y) * 256;

  const int srow8 = lane >> 3;                 // 0..7
  const int scol = ((lane & 7) ^ srow8) * 8;   // swizzled short offset

  f32x4 acc[8][4];
#pragma unroll
  for (int i = 0; i < 8; i++)
#pragma unroll
    for (int j = 0; j < 4; j++)
      acc[i][j] = f32x4{0.f, 0.f, 0.f, 0.f};

  const int nt = p.K >> 6;

  auto stage = [&](int buf, int t) {
    const long long k0 = (long long)t * 64;
#pragma unroll
    for (int h = 0; h < 4; h++)
      gload_lds16(p.A + (m0 + h * 64 + wid * 8 + srow8) * p.sAm + k0 + scol,
                  &lds[buf][0][(h * 64 + wid * 8) * 64]);
#pragma unroll
    for (int h = 0; h < 4; h++)
      gload_lds16(p.B + (n0 + h * 64 + wid * 8 + srow8) * p.sBn + k0 + scol,
                  &lds[buf][1][(h * 64 + wid * 8) * 64]);
  };

  stage(0, 0);
  stage(1, 1);

  for (int t = 0; t < nt; t++) {
    const int cur = t & 1;
    if (t + 1 < nt) asm volatile("s_waitcnt vmcnt(8)" ::: "memory");
    else            asm volatile("s_waitcnt vmcnt(0)" ::: "memory");
    __builtin_amdgcn_s_barrier();
    __builtin_amdgcn_sched_barrier(0);

    const unsigned short* Asb = lds[cur][0];
    const unsigned short* Bsb = lds[cur][1];
#pragma unroll
    for (int ks = 0; ks < 2; ks++) {
      const int c16 = ks * 4 + (lane >> 4);
      short8 a[8], b[4];
#pragma unroll
      for (int i = 0; i < 8; i++) {
        const int r = wm * 128 + i * 16 + (lane & 15);
        a[i] = *(const short8*)&Asb[r * 64 + ((c16 ^ (r & 7)) << 3)];
      }
#pragma unroll
      for (int j = 0; j < 4; j++) {
        const int r = wn * 64 + j * 16 + (lane & 15);
        b[j] = *(const short8*)&Bsb[r * 64 + ((c16 ^ (r & 7)) << 3)];
      }
      __builtin_amdgcn_s_setprio(1);
#pragma unroll
      for (int i = 0; i < 8; i++)
#pragma unroll
        for (int j = 0; j < 4; j++)
          acc[i][j] = __builtin_amdgcn_mfma_f32_16x16x32_bf16(a[i], b[j], acc[i][j], 0, 0, 0);
      __builtin_amdgcn_s_setprio(0);
    }
    __builtin_amdgcn_sched_barrier(0);
    __builtin_amdgcn_s_barrier();
    __builtin_amdgcn_sched_barrier(0);
    if (t + 2 < nt) stage(cur, t + 2);
  }

#pragma unroll
  for (int i = 0; i < 8; i++) {
#pragma unroll
    for (int j = 0; j < 4; j++) {
      const int col = (int)n0 + wn * 64 + j * 16 + (lane & 15);
      float bn = p.biasN ? p.biasN[col] : 0.f;
#pragma unroll
      for (int r = 0; r < 4; r++) {
        const long long row = m0 + wm * 128 + i * 16 + ((lane >> 4) << 2) + r;
        float v = acc[i][j][r] * p.scale + bn;
        if (p.relu) v = fmaxf(v, 0.f);
        const long long addr = row * p.sCm + col;
        if (p.cdtype == 0)      ((unsigned short*)p.C)[addr] = dev_f2bf(v);
        else if (p.cdtype == 3) ((float*)p.C)[addr] += v;
        else                    ((float*)p.C)[addr] = v;
      }
    }
  }
}

// ---------------------------------------------------------------------------
// Fully fused attention, QBLK=64: per block = 64 q-rows x one head z.
// LDS: u0 = [As 8KB | Bs 32KB] (Ps 32KB aliases u0 after phase 1), Vs 32KB.
// Total 73 KB -> 2 blocks/CU. Phases: QK^T -> in-reg softmax -> Ps(bf16,
// granule-XOR) -> PV -> bf16 store in place over the Q slice.
// ---------------------------------------------------------------------------
__global__ __launch_bounds__(256, 2) void attn_kernel(
    const unsigned short* __restrict__ Q, const unsigned short* __restrict__ EK,
    const unsigned short* __restrict__ EVt) {
  __shared__ __align__(16) unsigned short u0[20480];       // As(4096) + Bs(16384)
  __shared__ __align__(16) unsigned short Vs[64 * 256];    // 32 KB
  __shared__ float red[2][2][64];

  unsigned short* As = u0;           // 64 x 64
  unsigned short* Bs = u0 + 4096;    // 256 x 64
  unsigned short* Ps = u0;           // 64 x 256 (aliases As+Bs after QK phase)

  const int tid = threadIdx.x;
  const int lane = tid & 63;
  const int wid = tid >> 6;
  const int wm = wid >> 1, wn = wid & 1;   // 2x2 wave grid
  const int m0 = blockIdx.x * 64;
  const int z = blockIdx.z;
  unsigned short* Qz = (unsigned short*)Q + (long long)(z >> 4) * 4194304 + (long long)(z & 15) * 64;
  const unsigned short* EKz = EK + (long long)z * 16384;
  const unsigned short* EVz = EVt + (long long)z * 16384;

  const int srow = tid >> 3;
  const int scol = ((tid & 7) ^ (srow & 7)) * 8;

#pragma unroll
  for (int i = 0; i < 2; i++)
    gload_lds16(Qz + (long long)(m0 + i * 32 + srow) * 1024 + scol, &As[i * 2048 + wid * 512]);
#pragma unroll
  for (int i = 0; i < 8; i++)
    gload_lds16(EKz + (long long)(i * 32 + srow) * 64 + scol, &Bs[i * 2048 + wid * 512]);
  // EVt: physical granule pg holds logical granule (pg&31)^(d&7) of row d=pg>>5
#pragma unroll
  for (int c = 0; c < 8; c++) {
    const int pg = (c * 4 + wid) * 64 + lane;
    const int d = pg >> 5, gp = pg & 31;
    gload_lds16(EVz + d * 256 + ((gp ^ (d & 7)) << 3), &Vs[(c * 4 + wid) * 512]);
  }
  __syncthreads();

  f32x4 acc[2][8];
#pragma unroll
  for (int i = 0; i < 2; i++)
#pragma unroll
    for (int j = 0; j < 8; j++)
      acc[i][j] = f32x4{0.f, 0.f, 0.f, 0.f};

#pragma unroll
  for (int ks = 0; ks < 2; ks++) {
    const int c16 = ks * 4 + (lane >> 4);
    short8 a[2], b[8];
#pragma unroll
    for (int i = 0; i < 2; i++) {
      const int row = wm * 32 + i * 16 + (lane & 15);
      a[i] = *(const short8*)&As[row * 64 + ((c16 ^ (row & 7)) << 3)];
    }
#pragma unroll
    for (int j = 0; j < 8; j++) {
      const int row = wn * 128 + j * 16 + (lane & 15);
      b[j] = *(const short8*)&Bs[row * 64 + ((c16 ^ (row & 7)) << 3)];
    }
#pragma unroll
    for (int i = 0; i < 2; i++)
#pragma unroll
      for (int j = 0; j < 8; j++)
        acc[i][j] = __builtin_amdgcn_mfma_f32_16x16x32_bf16(a[i], b[j], acc[i][j], 0, 0, 0);
  }

  const int rr4 = (lane >> 4) << 2;
#pragma unroll
  for (int i = 0; i < 2; i++) {
#pragma unroll
    for (int r = 0; r < 4; r++) {
      float m = acc[i][0][r];
#pragma unroll
      for (int j = 1; j < 8; j++) m = fmaxf(m, acc[i][j][r]);
      m = fmaxf(m, __shfl_xor(m, 1));
      m = fmaxf(m, __shfl_xor(m, 2));
      m = fmaxf(m, __shfl_xor(m, 4));
      m = fmaxf(m, __shfl_xor(m, 8));
      if ((lane & 15) == 0) red[0][wn][wm * 32 + i * 16 + rr4 + r] = m;
    }
  }
  __syncthreads();
  float fm[2][4];
#pragma unroll
  for (int i = 0; i < 2; i++)
#pragma unroll
    for (int r = 0; r < 4; r++) {
      const int row = wm * 32 + i * 16 + rr4 + r;
      fm[i][r] = fmaxf(red[0][0][row], red[0][1][row]);
    }
#pragma unroll
  for (int i = 0; i < 2; i++) {
#pragma unroll
    for (int r = 0; r < 4; r++) {
      float s = 0.f;
#pragma unroll
      for (int j = 0; j < 8; j++) {
        float e = __expf((acc[i][j][r] - fm[i][r]) * 0.125f);
        acc[i][j][r] = e;
        s += e;
      }
      s += __shfl_xor(s, 1);
      s += __shfl_xor(s, 2);
      s += __shfl_xor(s, 4);
      s += __shfl_xor(s, 8);
      if ((lane & 15) == 0) red[1][wn][wm * 32 + i * 16 + rr4 + r] = s;
    }
  }
  __syncthreads();   // last As/Bs reads done; Ps may now overwrite u0
#pragma unroll
  for (int i = 0; i < 2; i++) {
#pragma unroll
    for (int r = 0; r < 4; r++) {
      const int row = wm * 32 + i * 16 + rr4 + r;
      const float inv = 1.f / (red[1][0][row] + red[1][1][row]);
#pragma unroll
      for (int j = 0; j < 8; j++) {
        const int col = wn * 128 + j * 16 + (lane & 15);
        Ps[row * 256 + (((col >> 3) ^ (row & 7)) << 3) + (col & 7)] =
            dev_f2bf(acc[i][j][r] * inv);
      }
    }
  }
  __syncthreads();

  // PV: out[q][d] = sum_k P[q,k] * EVt[d,k]; per wave 32q x 32d
  f32x4 acc2[2][2];
#pragma unroll
  for (int i = 0; i < 2; i++)
#pragma unroll
    for (int jj = 0; jj < 2; jj++)
      acc2[i][jj] = f32x4{0.f, 0.f, 0.f, 0.f};

#pragma unroll
  for (int ks = 0; ks < 8; ks++) {
    const int G = ks * 4 + (lane >> 4);
    short8 pa[2], pb[2];
#pragma unroll
    for (int i = 0; i < 2; i++) {
      const int row = wm * 32 + i * 16 + (lane & 15);
      pa[i] = *(const short8*)&Ps[row * 256 + ((G ^ (row & 7)) << 3)];
    }
#pragma unroll
    for (int jj = 0; jj < 2; jj++) {
      const int d = wn * 32 + jj * 16 + (lane & 15);
      pb[jj] = *(const short8*)&Vs[d * 256 + ((G ^ (d & 7)) << 3)];
    }
#pragma unroll
    for (int i = 0; i < 2; i++)
#pragma unroll
      for (int jj = 0; jj < 2; jj++)
        acc2[i][jj] = __builtin_amdgcn_mfma_f32_16x16x32_bf16(pa[i], pb[jj], acc2[i][jj], 0, 0, 0);
  }

#pragma unroll
  for (int i = 0; i < 2; i++) {
#pragma unroll
    for (int jj = 0; jj < 2; jj++) {
#pragma unroll
      for (int r = 0; r < 4; r++) {
        const int qrow = m0 + wm * 32 + i * 16 + rr4 + r;
        const int dcol = wn * 32 + jj * 16 + (lane & 15);
        Qz[(long long)qrow * 1024 + dcol] = dev_f2bf(acc2[i][jj][r]);
      }
    }
  }
}

// General NT GEMM (small/batched shapes): C[z,m,n] = scale*sum_k A[m,k]*B[n,k]
template<int BM, int BN, int WM, int WN>
__global__ __launch_bounds__(256, 2) void gemm_nt(GemmP p) {
  constexpr int BK = 64;
  constexpr int TM = BM / WM, TN = BN / WN;
  constexpr int FM = TM / 16, FN = TN / 16;
  __shared__ __align__(16) unsigned short As[BM * BK];
  __shared__ __align__(16) unsigned short Bs[BN * BK];

  const int tid = threadIdx.x;
  const int lane = tid & 63;
  const int wid = tid >> 6;
  const int wm = wid / WN, wn = wid % WN;
  const int m0 = blockIdx.x * BM;
  const int n0 = blockIdx.y * BN;
  const int z = blockIdx.z;
  const int zq = z >> 4, zr = z & 15;
  const unsigned short* Ag = p.A + (long long)zq * p.aHi + (long long)zr * p.aLo;
  const unsigned short* Bg = p.B + (long long)zq * p.bHi + (long long)zr * p.bLo;

  const int srow = tid >> 3;                      // 0..31
  const int scol = ((tid & 7) ^ (srow & 7)) * 8;  // swizzled 16B column
  constexpr int AC = BM / 32, BC = BN / 32;

  f32x4 acc[FM][FN];
#pragma unroll
  for (int i = 0; i < FM; i++)
#pragma unroll
    for (int j = 0; j < FN; j++)
      acc[i][j] = f32x4{0.f, 0.f, 0.f, 0.f};

  for (int k0 = 0; k0 < p.K; k0 += BK) {
#pragma unroll
    for (int i = 0; i < AC; i++)
      gload_lds16(Ag + (long long)(m0 + i * 32 + srow) * p.sAm + (k0 + scol),
                  &As[i * 2048 + wid * 512]);
#pragma unroll
    for (int i = 0; i < BC; i++)
      gload_lds16(Bg + (long long)(n0 + i * 32 + srow) * p.sBn + (k0 + scol),
                  &Bs[i * 2048 + wid * 512]);
    __syncthreads();
#pragma unroll
    for (int ks = 0; ks < 2; ks++) {
      const int c16 = ks * 4 + (lane >> 4);
      short8 a[FM], b[FN];
#pragma unroll
      for (int i = 0; i < FM; i++) {
        const int row = wm * TM + i * 16 + (lane & 15);
        a[i] = *(const short8*)&As[row * 64 + ((c16 ^ (row & 7)) << 3)];
      }
#pragma unroll
      for (int j = 0; j < FN; j++) {
        const int row = wn * TN + j * 16 + (lane & 15);
        b[j] = *(const short8*)&Bs[row * 64 + ((c16 ^ (row & 7)) << 3)];
      }
#pragma unroll
      for (int i = 0; i < FM; i++)
#pragma unroll
        for (int j = 0; j < FN; j++)
          acc[i][j] = __builtin_amdgcn_mfma_f32_16x16x32_bf16(a[i], b[j], acc[i][j], 0, 0, 0);
    }
    __syncthreads();
  }

  const long long zc_ = (long long)zq * p.cHi + (long long)zr * p.cLo;
#pragma unroll
  for (int i = 0; i < FM; i++) {
#pragma unroll
    for (int j = 0; j < FN; j++) {
      const int col = n0 + wn * TN + j * 16 + (lane & 15);
      float bn = p.biasN ? p.biasN[col] : 0.f;
#pragma unroll
      for (int r = 0; r < 4; r++) {
        const int row = m0 + wm * TM + i * 16 + ((lane >> 4) << 2) + r;
        float v = acc[i][j][r] * p.scale + bn;
        if (p.biasM) v += p.biasM[row];
        if (p.relu) v = fmaxf(v, 0.f);
        const long long addr = zc_ + (long long)row * p.sCm + (long long)col * p.sCn;
        if (p.cdtype == 0)      ((unsigned short*)p.C)[addr] = dev_f2bf(v);
        else if (p.cdtype == 3) ((float*)p.C)[addr] += v;
        else                    ((float*)p.C)[addr] = v;
      }
    }
  }
}

// 64x64 tiled transpose: in [b][4096][1024] -> out [b][1024][4096] (bf16)
__global__ __launch_bounds__(256) void transpose_kernel(const unsigned short* __restrict__ in,
                                                        unsigned short* __restrict__ out) {
  __shared__ unsigned short t[64][72];
  const int b = blockIdx.z;
  const int n0 = blockIdx.x * 64, c0 = blockIdx.y * 64;
  const int r = threadIdx.x >> 2;          // 0..63
  const int cc = (threadIdx.x & 3) * 16;   // 0,16,32,48
  const unsigned short* ip = in + (size_t)b * 4194304 + (size_t)n0 * 1024 + c0;
  *(short8*)&t[r][cc]     = *(const short8*)(ip + (size_t)r * 1024 + cc);
  *(short8*)&t[r][cc + 8] = *(const short8*)(ip + (size_t)r * 1024 + cc + 8);
  __syncthreads();
  unsigned short* op = out + (size_t)b * 4194304 + (size_t)c0 * 4096 + n0;
  short8 w0, w1;
#pragma unroll
  for (int j = 0; j < 8; j++) {
    w0[j] = (short)t[cc + j][r];
    w1[j] = (short)t[cc + 8 + j][r];
  }
  *(short8*)(op + (size_t)r * 4096 + cc)     = w0;
  *(short8*)(op + (size_t)r * 4096 + cc + 8) = w1;
}

// f32 -> bf16, x4 vectorized, grid-stride
__global__ void cvt_kernel(const float* __restrict__ src, unsigned short* __restrict__ dst,
                           long long n4) {
  long long i = (long long)blockIdx.x * blockDim.x + threadIdx.x;
  const long long stride = (long long)gridDim.x * blockDim.x;
  for (; i < n4; i += stride) {
    float4 v = ((const float4*)src)[i];
    ushort4 u;
    u.x = dev_f2bf(v.x); u.y = dev_f2bf(v.y); u.z = dev_f2bf(v.z); u.w = dev_f2bf(v.w);
    ((ushort4*)dst)[i] = u;
  }
}

// LN over rows of 1024: t = bf2f(xr) + y, where y = yf[row] (f32) if yf else
// bf2f(yr[row]). Writes bf16 LN(t) to xw (if non-null) and f32 LN(t) to fout
// (if non-null). fout may alias yf (per-row read-then-write, block-local).
__global__ __launch_bounds__(256) void add_ln_kernel(
    const unsigned short* __restrict__ xr, const unsigned short* __restrict__ yr,
    const float* __restrict__ yf,
    unsigned short* __restrict__ xw, float* __restrict__ fout,
    const float* __restrict__ g, const float* __restrict__ b) {
  const long long row = blockIdx.x;
  const int tid = threadIdx.x;
  ushort4 xv = ((const ushort4*)(xr + row * 1024))[tid];
  float4 t;
  if (yf) {
    float4 yv = ((const float4*)(yf + row * 1024))[tid];
    t = float4{dev_bf2f(xv.x) + yv.x, dev_bf2f(xv.y) + yv.y,
               dev_bf2f(xv.z) + yv.z, dev_bf2f(xv.w) + yv.w};
  } else {
    ushort4 yv = ((const ushort4*)(yr + row * 1024))[tid];
    t = float4{dev_bf2f(xv.x) + dev_bf2f(yv.x), dev_bf2f(xv.y) + dev_bf2f(yv.y),
               dev_bf2f(xv.z) + dev_bf2f(yv.z), dev_bf2f(xv.w) + dev_bf2f(yv.w)};
  }
  float s = t.x + t.y + t.z + t.w;
  float ss = t.x * t.x + t.y * t.y + t.z * t.z + t.w * t.w;
#pragma unroll
  for (int off = 32; off > 0; off >>= 1) { s += __shfl_xor(s, off); ss += __shfl_xor(ss, off); }
  __shared__ float sm[8];
  const int wid = tid >> 6, lane = tid & 63;
  if (lane == 0) { sm[wid] = s; sm[4 + wid] = ss; }
  __syncthreads();
  s = sm[0] + sm[1] + sm[2] + sm[3];
  ss = sm[4] + sm[5] + sm[6] + sm[7];
  const float mean = s * (1.f / 1024.f);
  const float var = ss * (1.f / 1024.f) - mean * mean;
  const float rs = rsqrtf(var + 1e-5f);
  float4 gv = ((const float4*)g)[tid];
  float4 bv = ((const float4*)b)[tid];
  float4 o = {(t.x - mean) * rs * gv.x + bv.x, (t.y - mean) * rs * gv.y + bv.y,
              (t.z - mean) * rs * gv.z + bv.z, (t.w - mean) * rs * gv.w + bv.w};
  if (xw) {
    ushort4 ob;
    ob.x = dev_f2bf(o.x); ob.y = dev_f2bf(o.y); ob.z = dev_f2bf(o.z); ob.w = dev_f2bf(o.w);
    ((ushort4*)(xw + row * 1024))[tid] = ob;
  }
  if (fout) ((float4*)(fout + row * 1024))[tid] = o;
}

// canary: unambiguous "workspace too small" signal (absmax ~ 100+max|ref|)
__global__ void fill_canary_kernel(float* p, long long n) {
  long long i = (long long)blockIdx.x * blockDim.x + threadIdx.x;
  const long long stride = (long long)gridDim.x * blockDim.x;
  for (; i < n; i += stride) p[i] = 100.0f;
}

extern "C" void kernel_launch(void* const* d_in, const int* in_sizes, int n_in,
                              void* d_out, int out_size, void* d_ws, size_t ws_size,
                              hipStream_t stream) {
  const float* x_in  = (const float*)d_in[0];
  const float* E_w   = (const float*)d_in[1];
  const float* E_b   = (const float*)d_in[2];
  const float* Wq    = (const float*)d_in[3];
  const float* Wk    = (const float*)d_in[4];
  const float* Wv    = (const float*)d_in[5];
  const float* wo_w  = (const float*)d_in[6];
  const float* wo_b  = (const float*)d_in[7];
  const float* ln1_g = (const float*)d_in[8];
  const float* ln1_b = (const float*)d_in[9];
  const float* ff_w1 = (const float*)d_in[10];
  const float* ff_b1 = (const float*)d_in[11];
  const float* ff_w2 = (const float*)d_in[12];
  const float* ff_b2 = (const float*)d_in[13];
  const float* ln2_g = (const float*)d_in[14];
  const float* ln2_b = (const float*)d_in[15];

  float* xfout = (float*)d_out;                   // final f32 output
  unsigned short* ybuf = (unsigned short*)d_out;  // bf16 y scratch (first 32 MiB of d_out)

  char* ws = (char*)d_ws;
  size_t off = 0;
  auto alloc = [&](size_t bytes) -> char* {
    char* p = ws + off;
    off = (off + bytes + 255) & ~(size_t)255;
    return p;
  };
  unsigned short* E16 = (unsigned short*)alloc(1048576ULL * 2);  // E_w bf16 [256,4096]
  unsigned short* Wq16 = (unsigned short*)alloc(2097152ULL * 2); // both layers
  unsigned short* Wk16 = (unsigned short*)alloc(2097152ULL * 2);
  unsigned short* Wv16 = (unsigned short*)alloc(2097152ULL * 2);
  unsigned short* Wo16 = (unsigned short*)alloc(2097152ULL * 2);
  unsigned short* F116 = (unsigned short*)alloc(8388608ULL * 2);
  unsigned short* F216 = (unsigned short*)alloc(8388608ULL * 2);
  unsigned short* xE  = (unsigned short*)alloc(1048576ULL * 2);  // [b][256][1024]
  unsigned short* EK  = (unsigned short*)alloc(1048576ULL * 2);  // [z][256][64]
  unsigned short* EVt = (unsigned short*)alloc(1048576ULL * 2);  // [z][64][256]
  unsigned short* xd  = (unsigned short*)alloc(16777216ULL * 2); // bf16 residual x
  unsigned short* xT  = (unsigned short*)alloc(16777216ULL * 2); // x^T; later Q/cat
  unsigned short* Qb4 = xT;   // alias: xT dead once pe is done; Q/cat [16384][1024]

  size_t rem = (ws_size > off) ? ws_size - off : 0;
  size_t Rbytes = rem > 512 ? rem - 512 : 0;
  if (Rbytes > 134217728ULL) Rbytes = 134217728ULL;
  int rowc = 16384;
  while (rowc > 256 && (size_t)rowc * 8192ULL > Rbytes) rowc >>= 1;
  if ((size_t)rowc * 8192ULL > Rbytes) {
    fill_canary_kernel<<<2048, 256, 0, stream>>>(xfout, (long long)out_size);
    return;
  }
  char* R = alloc(Rbytes);   // h buffer region

  auto cvt = [&](const float* s, unsigned short* d, long long n) {
    long long n4 = n / 4;
    int grid = (int)((n4 + 255) / 256);
    if (grid > 4096) grid = 4096;
    cvt_kernel<<<grid, 256, 0, stream>>>(s, d, n4);
  };

  // ---- all conversions once
  cvt(x_in, xd, 16777216);
  cvt(E_w, E16, 1048576);
  cvt(Wq, Wq16, 2097152);
  cvt(Wk, Wk16, 2097152);
  cvt(Wv, Wv16, 2097152);
  cvt(wo_w, Wo16, 2097152);
  cvt(ff_w1, F116, 8388608);
  cvt(ff_w2, F216, 8388608);

  for (int l = 0; l < 2; l++) {
    const unsigned short* WqL = Wq16 + (size_t)l * 1048576;
    const unsigned short* WkL = Wk16 + (size_t)l * 1048576;
    const unsigned short* WvL = Wv16 + (size_t)l * 1048576;
    const unsigned short* WoL = Wo16 + (size_t)l * 1048576;
    const unsigned short* F1L = F116 + (size_t)l * 4194304;
    const unsigned short* F2L = F216 + (size_t)l * 4194304;

    // ---- xT[b][c][n] = x[b][n][c]
    transpose_kernel<<<dim3(64, 16, 4), 256, 0, stream>>>(xd, xT);

    // ---- xE[b][k][c] = sum_n E_w[k,n] * xT[b][c][n]   (pure NT, z = b)
    GemmP pe{};
    pe.A = E16; pe.sAm = 4096; pe.K = 4096;
    pe.B = xT; pe.sBn = 4096; pe.bLo = 4194304;
    pe.C = xE; pe.cLo = 262144; pe.sCm = 1024; pe.sCn = 1;
    pe.scale = 1.f; pe.cdtype = 0;
    gemm_nt<64,64,2,2><<<dim3(4, 16, 4), 256, 0, stream>>>(pe);

    // ---- EK[z][k][d] = xE[b] @ Wk[h]^T + E_b[k]   (z = b*16+h)
    GemmP pk{};
    pk.A = xE; pk.sAm = 1024; pk.K = 1024; pk.aHi = 262144; pk.aLo = 0;
    pk.B = WkL; pk.sBn = 1024; pk.bHi = 0; pk.bLo = 65536;
    pk.C = EK; pk.cHi = 262144; pk.cLo = 16384; pk.sCm = 64; pk.sCn = 1;
    pk.biasM = E_b; pk.scale = 1.f; pk.cdtype = 0;
    gemm_nt<64,64,2,2><<<dim3(4, 1, 64), 256, 0, stream>>>(pk);
    // ---- EVt[z][d][k] = (xE[b] @ Wv[h]^T + E_b[k])^T
    GemmP pv2 = pk;
    pv2.B = WvL; pv2.C = EVt; pv2.sCm = 1; pv2.sCn = 256;
    gemm_nt<64,64,2,2><<<dim3(4, 1, 64), 256, 0, stream>>>(pv2);

    // ---- Q (all batches) = x @ Wq^T : [16384,1024]   (overwrites xT region)
    GemmP pq{};
    pq.A = xd; pq.sAm = 1024; pq.K = 1024;
    pq.B = WqL; pq.sBn = 1024;
    pq.C = Qb4; pq.sCm = 1024; pq.sCn = 1;
    pq.scale = 1.f; pq.cdtype = 0;
    gemm256<<<dim3(64, 4, 1), 512, 0, stream>>>(pq);

    // ---- fused attention: cat[b][n][h*64+d] overwrites Q slice in place
    attn_kernel<<<dim3(64, 1, 64), 256, 0, stream>>>(Qb4, EK, EVt);

    // ---- y = cat @ wo^T + wo_b -> bf16 ybuf (in d_out scratch)
    GemmP pw{};
    pw.A = Qb4; pw.sAm = 1024; pw.K = 1024;
    pw.B = WoL; pw.sBn = 1024;
    pw.biasN = wo_b + (size_t)l * 1024;
    pw.C = ybuf; pw.cdtype = 0;
    pw.sCm = 1024; pw.sCn = 1; pw.scale = 1.f;
    gemm256<<<dim3(64, 4, 1), 512, 0, stream>>>(pw);

    // ---- x = LN1(x + y)  (bf16 in, bf16 out)
    add_ln_kernel<<<16384, 256, 0, stream>>>(xd, ybuf, nullptr, xd, nullptr,
                                             ln1_g + (size_t)l * 1024,
                                             ln1_b + (size_t)l * 1024);

    // ---- FFN, row-chunked: h = relu(x@W1^T+b1) -> R; y = h@W2^T+b2
    for (int r0 = 0; r0 < 16384; r0 += rowc) {
      GemmP f1{};
      f1.A = xd + (size_t)r0 * 1024; f1.sAm = 1024; f1.K = 1024;
      f1.B = F1L; f1.sBn = 1024;
      f1.C = R; f1.sCm = 4096; f1.sCn = 1;
      f1.biasN = ff_b1 + (size_t)l * 4096; f1.scale = 1.f; f1.relu = 1; f1.cdtype = 0;
      gemm256<<<dim3(rowc / 256, 16, 1), 512, 0, stream>>>(f1);

      GemmP f2{};
      f2.A = (unsigned short*)R; f2.sAm = 4096; f2.K = 4096;
      f2.B = F2L; f2.sBn = 4096;
      f2.biasN = ff_b2 + (size_t)l * 1024;
      f2.sCm = 1024; f2.sCn = 1; f2.scale = 1.f;
      if (l == 1) { f2.C = xfout + (size_t)r0 * 1024; f2.cdtype = 1; }  // f32 y in d_out
      else        { f2.C = ybuf + (size_t)r0 * 1024;  f2.cdtype = 0; }
      gemm256<<<dim3(rowc / 256, 4, 1), 512, 0, stream>>>(f2);
    }
    // ---- x = LN2(x + y); final layer: y f32 in d_out, LN in-place f32 out
    if (l == 1)
      add_ln_kernel<<<16384, 256, 0, stream>>>(xd, nullptr, xfout, nullptr, xfout,
                                               ln2_g + 1024, ln2_b + 1024);
    else
      add_ln_kernel<<<16384, 256, 0, stream>>>(xd, ybuf, nullptr, xd, nullptr,
                                               ln2_g, ln2_b);
  }
}

// Round 14
// 1217.631 us; speedup vs baseline: 1.1823x; 1.0387x over previous
//
#include <hip/hip_runtime.h>
#include <hip/hip_bf16.h>

typedef __attribute__((ext_vector_type(8))) short short8;
typedef __attribute__((ext_vector_type(4))) float f32x4;

__device__ __forceinline__ unsigned short dev_f2bf(float f) {
  __hip_bfloat16 b = __float2bfloat16(f);
  union { __hip_bfloat16 b; unsigned short u; } c; c.b = b; return c.u;
}
__device__ __forceinline__ float dev_bf2f(unsigned short u) {
  union { unsigned int i; float f; } c; c.i = ((unsigned int)u) << 16; return c.f;
}

// async global->LDS, 16B per lane; dest = lds_base(wave-uniform) + lane*16
__device__ __forceinline__ void gload_lds16(const unsigned short* g, unsigned short* l) {
  __builtin_amdgcn_global_load_lds(
      (const __attribute__((address_space(1))) void*)(const void*)g,
      (__attribute__((address_space(3))) void*)(void*)l, 16, 0, 0);
}

struct GemmP {
  const unsigned short* A;   // bf16 bits
  const unsigned short* B;   // bf16 bits
  void* C;
  const float* biasN;        // bias by output col, may be null
  const float* biasM;        // bias by output row, may be null
  long long aHi, aLo, bHi, bLo, cHi, cLo;  // per-z base: (z>>4)*Hi + (z&15)*Lo
  int K;
  int sAm;                   // A row stride (k stride == 1)
  int sBn;                   // B row stride (k stride == 1)
  int sCm, sCn;
  float scale;
  int relu;
  int cdtype;                // 0=bf16, 1=f32, 3=f32 +=
};

// ---------------------------------------------------------------------------
// Big-GEMM: 256x256 tile, 512 threads (8 waves, 2Mx4N), BK=64, double-buffered
// LDS with counted vmcnt pipeline (never drains to 0 in main loop).
// LDS(row, c16) holds global(row, c16 ^ (row&7)); reads apply the same XOR.
// XCD swizzle (nwg%8==0): A-GROUPED decode. Stage addresses hoisted: one
// base mul per operand, per-call = base + h*64*stride + t*64.
// ---------------------------------------------------------------------------
__global__ __launch_bounds__(512, 2) void gemm256(GemmP p) {
  __shared__ __align__(16) unsigned short lds[2][2][256 * 64];  // 128 KiB

  const int tid = threadIdx.x;
  const int lane = tid & 63;
  const int wid = tid >> 6;       // 0..7
  const int wm = wid >> 2;        // 0..1
  const int wn = wid & 3;         // 0..3

  int id = blockIdx.y * gridDim.x + blockIdx.x;
  const int nwg = gridDim.x * gridDim.y;
  if ((nwg & 7) == 0) id = (id & 7) * (nwg >> 3) + (id >> 3);
  const long long m0 = (long long)(id / gridDim.y) * 256;   // A-grouped decode
  const long long n0 = (long long)(id % gridDim.y) * 256;

  const int srow8 = lane >> 3;                 // 0..7
  const int scol = ((lane & 7) ^ srow8) * 8;   // swizzled short offset

  // hoisted stage bases (one 64-bit mul each)
  const long long sA64 = 64LL * p.sAm, sB64 = 64LL * p.sBn;
  const unsigned short* aBase = p.A + (m0 + wid * 8 + srow8) * (long long)p.sAm + scol;
  const unsigned short* bBase = p.B + (n0 + wid * 8 + srow8) * (long long)p.sBn + scol;

  f32x4 acc[8][4];
#pragma unroll
  for (int i = 0; i < 8; i++)
#pragma unroll
    for (int j = 0; j < 4; j++)
      acc[i][j] = f32x4{0.f, 0.f, 0.f, 0.f};

  const int nt = p.K >> 6;

  auto stage = [&](int buf, int t) {
    const long long k0 = (long long)t * 64;
#pragma unroll
    for (int h = 0; h < 4; h++)
      gload_lds16(aBase + h * sA64 + k0, &lds[buf][0][(h * 64 + wid * 8) * 64]);
#pragma unroll
    for (int h = 0; h < 4; h++)
      gload_lds16(bBase + h * sB64 + k0, &lds[buf][1][(h * 64 + wid * 8) * 64]);
  };

  stage(0, 0);
  stage(1, 1);

  for (int t = 0; t < nt; t++) {
    const int cur = t & 1;
    if (t + 1 < nt) asm volatile("s_waitcnt vmcnt(8)" ::: "memory");
    else            asm volatile("s_waitcnt vmcnt(0)" ::: "memory");
    __builtin_amdgcn_s_barrier();
    __builtin_amdgcn_sched_barrier(0);

    const unsigned short* Asb = lds[cur][0];
    const unsigned short* Bsb = lds[cur][1];
#pragma unroll
    for (int ks = 0; ks < 2; ks++) {
      const int c16 = ks * 4 + (lane >> 4);
      short8 a[8], b[4];
#pragma unroll
      for (int i = 0; i < 8; i++) {
        const int r = wm * 128 + i * 16 + (lane & 15);
        a[i] = *(const short8*)&Asb[r * 64 + ((c16 ^ (r & 7)) << 3)];
      }
#pragma unroll
      for (int j = 0; j < 4; j++) {
        const int r = wn * 64 + j * 16 + (lane & 15);
        b[j] = *(const short8*)&Bsb[r * 64 + ((c16 ^ (r & 7)) << 3)];
      }
      __builtin_amdgcn_s_setprio(1);
#pragma unroll
      for (int i = 0; i < 8; i++)
#pragma unroll
        for (int j = 0; j < 4; j++)
          acc[i][j] = __builtin_amdgcn_mfma_f32_16x16x32_bf16(a[i], b[j], acc[i][j], 0, 0, 0);
      __builtin_amdgcn_s_setprio(0);
    }
    __builtin_amdgcn_sched_barrier(0);
    __builtin_amdgcn_s_barrier();
    __builtin_amdgcn_sched_barrier(0);
    if (t + 2 < nt) stage(cur, t + 2);
  }

#pragma unroll
  for (int i = 0; i < 8; i++) {
#pragma unroll
    for (int j = 0; j < 4; j++) {
      const int col = (int)n0 + wn * 64 + j * 16 + (lane & 15);
      float bn = p.biasN ? p.biasN[col] : 0.f;
#pragma unroll
      for (int r = 0; r < 4; r++) {
        const long long row = m0 + wm * 128 + i * 16 + ((lane >> 4) << 2) + r;
        float v = acc[i][j][r] * p.scale + bn;
        if (p.relu) v = fmaxf(v, 0.f);
        const long long addr = row * p.sCm + col;
        if (p.cdtype == 0)      ((unsigned short*)p.C)[addr] = dev_f2bf(v);
        else if (p.cdtype == 3) ((float*)p.C)[addr] += v;
        else                    ((float*)p.C)[addr] = v;
      }
    }
  }
}

// ---------------------------------------------------------------------------
// Fully fused attention, QBLK=64: per block = 64 q-rows x one head z.
// LDS: u0 = [As 8KB | Bs 32KB] (Ps 32KB aliases u0 after phase 1), Vs 32KB.
// Total 73 KB -> 2 blocks/CU. Phases: QK^T -> in-reg softmax -> Ps(bf16,
// granule-XOR) -> PV -> bf16 store in place over the Q slice.
// ---------------------------------------------------------------------------
__global__ __launch_bounds__(256, 2) void attn_kernel(
    const unsigned short* __restrict__ Q, const unsigned short* __restrict__ EK,
    const unsigned short* __restrict__ EVt) {
  __shared__ __align__(16) unsigned short u0[20480];       // As(4096) + Bs(16384)
  __shared__ __align__(16) unsigned short Vs[64 * 256];    // 32 KB
  __shared__ float red[2][2][64];

  unsigned short* As = u0;           // 64 x 64
  unsigned short* Bs = u0 + 4096;    // 256 x 64
  unsigned short* Ps = u0;           // 64 x 256 (aliases As+Bs after QK phase)

  const int tid = threadIdx.x;
  const int lane = tid & 63;
  const int wid = tid >> 6;
  const int wm = wid >> 1, wn = wid & 1;   // 2x2 wave grid
  const int m0 = blockIdx.x * 64;
  const int z = blockIdx.z;
  unsigned short* Qz = (unsigned short*)Q + (long long)(z >> 4) * 4194304 + (long long)(z & 15) * 64;
  const unsigned short* EKz = EK + (long long)z * 16384;
  const unsigned short* EVz = EVt + (long long)z * 16384;

  const int srow = tid >> 3;
  const int scol = ((tid & 7) ^ (srow & 7)) * 8;

#pragma unroll
  for (int i = 0; i < 2; i++)
    gload_lds16(Qz + (long long)(m0 + i * 32 + srow) * 1024 + scol, &As[i * 2048 + wid * 512]);
#pragma unroll
  for (int i = 0; i < 8; i++)
    gload_lds16(EKz + (long long)(i * 32 + srow) * 64 + scol, &Bs[i * 2048 + wid * 512]);
  // EVt: physical granule pg holds logical granule (pg&31)^(d&7) of row d=pg>>5
#pragma unroll
  for (int c = 0; c < 8; c++) {
    const int pg = (c * 4 + wid) * 64 + lane;
    const int d = pg >> 5, gp = pg & 31;
    gload_lds16(EVz + d * 256 + ((gp ^ (d & 7)) << 3), &Vs[(c * 4 + wid) * 512]);
  }
  __syncthreads();

  f32x4 acc[2][8];
#pragma unroll
  for (int i = 0; i < 2; i++)
#pragma unroll
    for (int j = 0; j < 8; j++)
      acc[i][j] = f32x4{0.f, 0.f, 0.f, 0.f};

#pragma unroll
  for (int ks = 0; ks < 2; ks++) {
    const int c16 = ks * 4 + (lane >> 4);
    short8 a[2], b[8];
#pragma unroll
    for (int i = 0; i < 2; i++) {
      const int row = wm * 32 + i * 16 + (lane & 15);
      a[i] = *(const short8*)&As[row * 64 + ((c16 ^ (row & 7)) << 3)];
    }
#pragma unroll
    for (int j = 0; j < 8; j++) {
      const int row = wn * 128 + j * 16 + (lane & 15);
      b[j] = *(const short8*)&Bs[row * 64 + ((c16 ^ (row & 7)) << 3)];
    }
#pragma unroll
    for (int i = 0; i < 2; i++)
#pragma unroll
      for (int j = 0; j < 8; j++)
        acc[i][j] = __builtin_amdgcn_mfma_f32_16x16x32_bf16(a[i], b[j], acc[i][j], 0, 0, 0);
  }

  const int rr4 = (lane >> 4) << 2;
#pragma unroll
  for (int i = 0; i < 2; i++) {
#pragma unroll
    for (int r = 0; r < 4; r++) {
      float m = acc[i][0][r];
#pragma unroll
      for (int j = 1; j < 8; j++) m = fmaxf(m, acc[i][j][r]);
      m = fmaxf(m, __shfl_xor(m, 1));
      m = fmaxf(m, __shfl_xor(m, 2));
      m = fmaxf(m, __shfl_xor(m, 4));
      m = fmaxf(m, __shfl_xor(m, 8));
      if ((lane & 15) == 0) red[0][wn][wm * 32 + i * 16 + rr4 + r] = m;
    }
  }
  __syncthreads();
  float fm[2][4];
#pragma unroll
  for (int i = 0; i < 2; i++)
#pragma unroll
    for (int r = 0; r < 4; r++) {
      const int row = wm * 32 + i * 16 + rr4 + r;
      fm[i][r] = fmaxf(red[0][0][row], red[0][1][row]);
    }
#pragma unroll
  for (int i = 0; i < 2; i++) {
#pragma unroll
    for (int r = 0; r < 4; r++) {
      float s = 0.f;
#pragma unroll
      for (int j = 0; j < 8; j++) {
        float e = __expf((acc[i][j][r] - fm[i][r]) * 0.125f);
        acc[i][j][r] = e;
        s += e;
      }
      s += __shfl_xor(s, 1);
      s += __shfl_xor(s, 2);
      s += __shfl_xor(s, 4);
      s += __shfl_xor(s, 8);
      if ((lane & 15) == 0) red[1][wn][wm * 32 + i * 16 + rr4 + r] = s;
    }
  }
  __syncthreads();   // last As/Bs reads done; Ps may now overwrite u0
#pragma unroll
  for (int i = 0; i < 2; i++) {
#pragma unroll
    for (int r = 0; r < 4; r++) {
      const int row = wm * 32 + i * 16 + rr4 + r;
      const float inv = 1.f / (red[1][0][row] + red[1][1][row]);
#pragma unroll
      for (int j = 0; j < 8; j++) {
        const int col = wn * 128 + j * 16 + (lane & 15);
        Ps[row * 256 + (((col >> 3) ^ (row & 7)) << 3) + (col & 7)] =
            dev_f2bf(acc[i][j][r] * inv);
      }
    }
  }
  __syncthreads();

  // PV: out[q][d] = sum_k P[q,k] * EVt[d,k]; per wave 32q x 32d
  f32x4 acc2[2][2];
#pragma unroll
  for (int i = 0; i < 2; i++)
#pragma unroll
    for (int jj = 0; jj < 2; jj++)
      acc2[i][jj] = f32x4{0.f, 0.f, 0.f, 0.f};

#pragma unroll
  for (int ks = 0; ks < 8; ks++) {
    const int G = ks * 4 + (lane >> 4);
    short8 pa[2], pb[2];
#pragma unroll
    for (int i = 0; i < 2; i++) {
      const int row = wm * 32 + i * 16 + (lane & 15);
      pa[i] = *(const short8*)&Ps[row * 256 + ((G ^ (row & 7)) << 3)];
    }
#pragma unroll
    for (int jj = 0; jj < 2; jj++) {
      const int d = wn * 32 + jj * 16 + (lane & 15);
      pb[jj] = *(const short8*)&Vs[d * 256 + ((G ^ (d & 7)) << 3)];
    }
#pragma unroll
    for (int i = 0; i < 2; i++)
#pragma unroll
      for (int jj = 0; jj < 2; jj++)
        acc2[i][jj] = __builtin_amdgcn_mfma_f32_16x16x32_bf16(pa[i], pb[jj], acc2[i][jj], 0, 0, 0);
  }

#pragma unroll
  for (int i = 0; i < 2; i++) {
#pragma unroll
    for (int jj = 0; jj < 2; jj++) {
#pragma unroll
      for (int r = 0; r < 4; r++) {
        const int qrow = m0 + wm * 32 + i * 16 + rr4 + r;
        const int dcol = wn * 32 + jj * 16 + (lane & 15);
        Qz[(long long)qrow * 1024 + dcol] = dev_f2bf(acc2[i][jj][r]);
      }
    }
  }
}

// ---------------------------------------------------------------------------
// Combined EK/EVt kernel: grid (4,1,128). z<64 -> EK[zz][k][d] = xE[b]@Wk[h]^T
// + E_b[k]; z>=64 -> EVt[zz][d][k] = (xE[b]@Wv[h]^T + E_b[k])^T. zz=z&63,
// b=zz>>4, h=zz&15. 64x64 tile, 4 waves 2x2, BK=64, same swizzled staging.
// ---------------------------------------------------------------------------
__global__ __launch_bounds__(256, 2) void ekv_kernel(
    const unsigned short* __restrict__ xE, const unsigned short* __restrict__ Wk,
    const unsigned short* __restrict__ Wv, const float* __restrict__ E_b,
    unsigned short* __restrict__ EK, unsigned short* __restrict__ EVt) {
  __shared__ __align__(16) unsigned short As[64 * 64];
  __shared__ __align__(16) unsigned short Bs[64 * 64];

  const int tid = threadIdx.x;
  const int lane = tid & 63;
  const int wid = tid >> 6;
  const int wm = wid >> 1, wn = wid & 1;
  const int z = blockIdx.z;
  const int isv = z >> 6;          // 0 = K, 1 = V
  const int zz = z & 63;
  const int b = zz >> 4, h = zz & 15;
  const int m0 = blockIdx.x * 64;

  const unsigned short* Ag = xE + (long long)b * 262144;
  const unsigned short* Bg = (isv ? Wv : Wk) + (long long)h * 65536;

  const int srow = tid >> 3;                      // 0..31
  const int scol = ((tid & 7) ^ (srow & 7)) * 8;  // swizzled 16B column

  f32x4 acc[2][2];
#pragma unroll
  for (int i = 0; i < 2; i++)
#pragma unroll
    for (int j = 0; j < 2; j++)
      acc[i][j] = f32x4{0.f, 0.f, 0.f, 0.f};

  for (int k0 = 0; k0 < 1024; k0 += 64) {
#pragma unroll
    for (int i = 0; i < 2; i++)
      gload_lds16(Ag + (long long)(m0 + i * 32 + srow) * 1024 + (k0 + scol),
                  &As[i * 2048 + wid * 512]);
#pragma unroll
    for (int i = 0; i < 2; i++)
      gload_lds16(Bg + (long long)(i * 32 + srow) * 1024 + (k0 + scol),
                  &Bs[i * 2048 + wid * 512]);
    __syncthreads();
#pragma unroll
    for (int ks = 0; ks < 2; ks++) {
      const int c16 = ks * 4 + (lane >> 4);
      short8 a[2], bfr[2];
#pragma unroll
      for (int i = 0; i < 2; i++) {
        const int row = wm * 32 + i * 16 + (lane & 15);
        a[i] = *(const short8*)&As[row * 64 + ((c16 ^ (row & 7)) << 3)];
      }
#pragma unroll
      for (int j = 0; j < 2; j++) {
        const int row = wn * 32 + j * 16 + (lane & 15);
        bfr[j] = *(const short8*)&Bs[row * 64 + ((c16 ^ (row & 7)) << 3)];
      }
#pragma unroll
      for (int i = 0; i < 2; i++)
#pragma unroll
        for (int j = 0; j < 2; j++)
          acc[i][j] = __builtin_amdgcn_mfma_f32_16x16x32_bf16(a[i], bfr[j], acc[i][j], 0, 0, 0);
    }
    __syncthreads();
  }

  const long long cb = (long long)zz * 16384;
#pragma unroll
  for (int i = 0; i < 2; i++) {
#pragma unroll
    for (int j = 0; j < 2; j++) {
      const int col = wn * 32 + j * 16 + (lane & 15);
#pragma unroll
      for (int r = 0; r < 4; r++) {
        const int row = m0 + wm * 32 + i * 16 + ((lane >> 4) << 2) + r;
        const float v = acc[i][j][r] + E_b[row];
        if (isv) EVt[cb + (long long)col * 256 + row] = dev_f2bf(v);
        else     EK[cb + (long long)row * 64 + col] = dev_f2bf(v);
      }
    }
  }
}

// General NT GEMM (small/batched shapes): C[z,m,n] = scale*sum_k A[m,k]*B[n,k]
template<int BM, int BN, int WM, int WN>
__global__ __launch_bounds__(256, 2) void gemm_nt(GemmP p) {
  constexpr int BK = 64;
  constexpr int TM = BM / WM, TN = BN / WN;
  constexpr int FM = TM / 16, FN = TN / 16;
  __shared__ __align__(16) unsigned short As[BM * BK];
  __shared__ __align__(16) unsigned short Bs[BN * BK];

  const int tid = threadIdx.x;
  const int lane = tid & 63;
  const int wid = tid >> 6;
  const int wm = wid / WN, wn = wid % WN;
  const int m0 = blockIdx.x * BM;
  const int n0 = blockIdx.y * BN;
  const int z = blockIdx.z;
  const int zq = z >> 4, zr = z & 15;
  const unsigned short* Ag = p.A + (long long)zq * p.aHi + (long long)zr * p.aLo;
  const unsigned short* Bg = p.B + (long long)zq * p.bHi + (long long)zr * p.bLo;

  const int srow = tid >> 3;                      // 0..31
  const int scol = ((tid & 7) ^ (srow & 7)) * 8;  // swizzled 16B column
  constexpr int AC = BM / 32, BC = BN / 32;

  f32x4 acc[FM][FN];
#pragma unroll
  for (int i = 0; i < FM; i++)
#pragma unroll
    for (int j = 0; j < FN; j++)
      acc[i][j] = f32x4{0.f, 0.f, 0.f, 0.f};

  for (int k0 = 0; k0 < p.K; k0 += BK) {
#pragma unroll
    for (int i = 0; i < AC; i++)
      gload_lds16(Ag + (long long)(m0 + i * 32 + srow) * p.sAm + (k0 + scol),
                  &As[i * 2048 + wid * 512]);
#pragma unroll
    for (int i = 0; i < BC; i++)
      gload_lds16(Bg + (long long)(n0 + i * 32 + srow) * p.sBn + (k0 + scol),
                  &Bs[i * 2048 + wid * 512]);
    __syncthreads();
#pragma unroll
    for (int ks = 0; ks < 2; ks++) {
      const int c16 = ks * 4 + (lane >> 4);
      short8 a[FM], b[FN];
#pragma unroll
      for (int i = 0; i < FM; i++) {
        const int row = wm * TM + i * 16 + (lane & 15);
        a[i] = *(const short8*)&As[row * 64 + ((c16 ^ (row & 7)) << 3)];
      }
#pragma unroll
      for (int j = 0; j < FN; j++) {
        const int row = wn * TN + j * 16 + (lane & 15);
        b[j] = *(const short8*)&Bs[row * 64 + ((c16 ^ (row & 7)) << 3)];
      }
#pragma unroll
      for (int i = 0; i < FM; i++)
#pragma unroll
        for (int j = 0; j < FN; j++)
          acc[i][j] = __builtin_amdgcn_mfma_f32_16x16x32_bf16(a[i], b[j], acc[i][j], 0, 0, 0);
    }
    __syncthreads();
  }

  const long long zc_ = (long long)zq * p.cHi + (long long)zr * p.cLo;
#pragma unroll
  for (int i = 0; i < FM; i++) {
#pragma unroll
    for (int j = 0; j < FN; j++) {
      const int col = n0 + wn * TN + j * 16 + (lane & 15);
      float bn = p.biasN ? p.biasN[col] : 0.f;
#pragma unroll
      for (int r = 0; r < 4; r++) {
        const int row = m0 + wm * TM + i * 16 + ((lane >> 4) << 2) + r;
        float v = acc[i][j][r] * p.scale + bn;
        if (p.biasM) v += p.biasM[row];
        if (p.relu) v = fmaxf(v, 0.f);
        const long long addr = zc_ + (long long)row * p.sCm + (long long)col * p.sCn;
        if (p.cdtype == 0)      ((unsigned short*)p.C)[addr] = dev_f2bf(v);
        else if (p.cdtype == 3) ((float*)p.C)[addr] += v;
        else                    ((float*)p.C)[addr] = v;
      }
    }
  }
}

// 64x64 tiled transpose: in [b][4096][1024] -> out [b][1024][4096] (bf16)
__global__ __launch_bounds__(256) void transpose_kernel(const unsigned short* __restrict__ in,
                                                        unsigned short* __restrict__ out) {
  __shared__ unsigned short t[64][72];
  const int b = blockIdx.z;
  const int n0 = blockIdx.x * 64, c0 = blockIdx.y * 64;
  const int r = threadIdx.x >> 2;          // 0..63
  const int cc = (threadIdx.x & 3) * 16;   // 0,16,32,48
  const unsigned short* ip = in + (size_t)b * 4194304 + (size_t)n0 * 1024 + c0;
  *(short8*)&t[r][cc]     = *(const short8*)(ip + (size_t)r * 1024 + cc);
  *(short8*)&t[r][cc + 8] = *(const short8*)(ip + (size_t)r * 1024 + cc + 8);
  __syncthreads();
  unsigned short* op = out + (size_t)b * 4194304 + (size_t)c0 * 4096 + n0;
  short8 w0, w1;
#pragma unroll
  for (int j = 0; j < 8; j++) {
    w0[j] = (short)t[cc + j][r];
    w1[j] = (short)t[cc + 8 + j][r];
  }
  *(short8*)(op + (size_t)r * 4096 + cc)     = w0;
  *(short8*)(op + (size_t)r * 4096 + cc + 8) = w1;
}

// segmented f32 -> bf16 convert: all 8 segments in one launch
struct CvtSegs {
  const float* src[8];
  unsigned short* dst[8];
  long long n4[8];
};
__global__ void cvt_all_kernel(CvtSegs s) {
  const long long stride = (long long)gridDim.x * blockDim.x;
#pragma unroll
  for (int seg = 0; seg < 8; seg++) {
    const float4* sp = (const float4*)s.src[seg];
    ushort4* dp = (ushort4*)s.dst[seg];
    const long long n4 = s.n4[seg];
    for (long long i = (long long)blockIdx.x * blockDim.x + threadIdx.x; i < n4; i += stride) {
      float4 v = sp[i];
      ushort4 u;
      u.x = dev_f2bf(v.x); u.y = dev_f2bf(v.y); u.z = dev_f2bf(v.z); u.w = dev_f2bf(v.w);
      dp[i] = u;
    }
  }
}

// LN over rows of 1024: t = bf2f(xr) + y, where y = yf[row] (f32) if yf else
// bf2f(yr[row]). Writes bf16 LN(t) to xw (if non-null) and f32 LN(t) to fout
// (if non-null). fout may alias yf (per-row read-then-write, block-local).
__global__ __launch_bounds__(256) void add_ln_kernel(
    const unsigned short* __restrict__ xr, const unsigned short* __restrict__ yr,
    const float* __restrict__ yf,
    unsigned short* __restrict__ xw, float* __restrict__ fout,
    const float* __restrict__ g, const float* __restrict__ b) {
  const long long row = blockIdx.x;
  const int tid = threadIdx.x;
  ushort4 xv = ((const ushort4*)(xr + row * 1024))[tid];
  float4 t;
  if (yf) {
    float4 yv = ((const float4*)(yf + row * 1024))[tid];
    t = float4{dev_bf2f(xv.x) + yv.x, dev_bf2f(xv.y) + yv.y,
               dev_bf2f(xv.z) + yv.z, dev_bf2f(xv.w) + yv.w};
  } else {
    ushort4 yv = ((const ushort4*)(yr + row * 1024))[tid];
    t = float4{dev_bf2f(xv.x) + dev_bf2f(yv.x), dev_bf2f(xv.y) + dev_bf2f(yv.y),
               dev_bf2f(xv.z) + dev_bf2f(yv.z), dev_bf2f(xv.w) + dev_bf2f(yv.w)};
  }
  float s = t.x + t.y + t.z + t.w;
  float ss = t.x * t.x + t.y * t.y + t.z * t.z + t.w * t.w;
#pragma unroll
  for (int off = 32; off > 0; off >>= 1) { s += __shfl_xor(s, off); ss += __shfl_xor(ss, off); }
  __shared__ float sm[8];
  const int wid = tid >> 6, lane = tid & 63;
  if (lane == 0) { sm[wid] = s; sm[4 + wid] = ss; }
  __syncthreads();
  s = sm[0] + sm[1] + sm[2] + sm[3];
  ss = sm[4] + sm[5] + sm[6] + sm[7];
  const float mean = s * (1.f / 1024.f);
  const float var = ss * (1.f / 1024.f) - mean * mean;
  const float rs = rsqrtf(var + 1e-5f);
  float4 gv = ((const float4*)g)[tid];
  float4 bv = ((const float4*)b)[tid];
  float4 o = {(t.x - mean) * rs * gv.x + bv.x, (t.y - mean) * rs * gv.y + bv.y,
              (t.z - mean) * rs * gv.z + bv.z, (t.w - mean) * rs * gv.w + bv.w};
  if (xw) {
    ushort4 ob;
    ob.x = dev_f2bf(o.x); ob.y = dev_f2bf(o.y); ob.z = dev_f2bf(o.z); ob.w = dev_f2bf(o.w);
    ((ushort4*)(xw + row * 1024))[tid] = ob;
  }
  if (fout) ((float4*)(fout + row * 1024))[tid] = o;
}

// canary: unambiguous "workspace too small" signal (absmax ~ 100+max|ref|)
__global__ void fill_canary_kernel(float* p, long long n) {
  long long i = (long long)blockIdx.x * blockDim.x + threadIdx.x;
  const long long stride = (long long)gridDim.x * blockDim.x;
  for (; i < n; i += stride) p[i] = 100.0f;
}

extern "C" void kernel_launch(void* const* d_in, const int* in_sizes, int n_in,
                              void* d_out, int out_size, void* d_ws, size_t ws_size,
                              hipStream_t stream) {
  const float* x_in  = (const float*)d_in[0];
  const float* E_w   = (const float*)d_in[1];
  const float* E_b   = (const float*)d_in[2];
  const float* Wq    = (const float*)d_in[3];
  const float* Wk    = (const float*)d_in[4];
  const float* Wv    = (const float*)d_in[5];
  const float* wo_w  = (const float*)d_in[6];
  const float* wo_b  = (const float*)d_in[7];
  const float* ln1_g = (const float*)d_in[8];
  const float* ln1_b = (const float*)d_in[9];
  const float* ff_w1 = (const float*)d_in[10];
  const float* ff_b1 = (const float*)d_in[11];
  const float* ff_w2 = (const float*)d_in[12];
  const float* ff_b2 = (const float*)d_in[13];
  const float* ln2_g = (const float*)d_in[14];
  const float* ln2_b = (const float*)d_in[15];

  float* xfout = (float*)d_out;                   // final f32 output
  unsigned short* ybuf = (unsigned short*)d_out;  // bf16 y scratch (first 32 MiB of d_out)

  char* ws = (char*)d_ws;
  size_t off = 0;
  auto alloc = [&](size_t bytes) -> char* {
    char* p = ws + off;
    off = (off + bytes + 255) & ~(size_t)255;
    return p;
  };
  unsigned short* E16 = (unsigned short*)alloc(1048576ULL * 2);  // E_w bf16 [256,4096]
  unsigned short* Wq16 = (unsigned short*)alloc(2097152ULL * 2); // both layers
  unsigned short* Wk16 = (unsigned short*)alloc(2097152ULL * 2);
  unsigned short* Wv16 = (unsigned short*)alloc(2097152ULL * 2);
  unsigned short* Wo16 = (unsigned short*)alloc(2097152ULL * 2);
  unsigned short* F116 = (unsigned short*)alloc(8388608ULL * 2);
  unsigned short* F216 = (unsigned short*)alloc(8388608ULL * 2);
  unsigned short* xE  = (unsigned short*)alloc(1048576ULL * 2);  // [b][256][1024]
  unsigned short* EK  = (unsigned short*)alloc(1048576ULL * 2);  // [z][256][64]
  unsigned short* EVt = (unsigned short*)alloc(1048576ULL * 2);  // [z][64][256]
  unsigned short* xd  = (unsigned short*)alloc(16777216ULL * 2); // bf16 residual x
  unsigned short* xT  = (unsigned short*)alloc(16777216ULL * 2); // x^T; later Q/cat
  unsigned short* Qb4 = xT;   // alias: xT dead once pe is done; Q/cat [16384][1024]

  size_t rem = (ws_size > off) ? ws_size - off : 0;
  size_t Rbytes = rem > 512 ? rem - 512 : 0;
  if (Rbytes > 134217728ULL) Rbytes = 134217728ULL;
  int rowc = 16384;
  while (rowc > 256 && (size_t)rowc * 8192ULL > Rbytes) rowc >>= 1;
  if ((size_t)rowc * 8192ULL > Rbytes) {
    fill_canary_kernel<<<2048, 256, 0, stream>>>(xfout, (long long)out_size);
    return;
  }
  char* R = alloc(Rbytes);   // h buffer region

  // ---- all conversions in one launch
  CvtSegs segs;
  segs.src[0] = x_in;  segs.dst[0] = xd;   segs.n4[0] = 16777216 / 4;
  segs.src[1] = E_w;   segs.dst[1] = E16;  segs.n4[1] = 1048576 / 4;
  segs.src[2] = Wq;    segs.dst[2] = Wq16; segs.n4[2] = 2097152 / 4;
  segs.src[3] = Wk;    segs.dst[3] = Wk16; segs.n4[3] = 2097152 / 4;
  segs.src[4] = Wv;    segs.dst[4] = Wv16; segs.n4[4] = 2097152 / 4;
  segs.src[5] = wo_w;  segs.dst[5] = Wo16; segs.n4[5] = 2097152 / 4;
  segs.src[6] = ff_w1; segs.dst[6] = F116; segs.n4[6] = 8388608 / 4;
  segs.src[7] = ff_w2; segs.dst[7] = F216; segs.n4[7] = 8388608 / 4;
  cvt_all_kernel<<<2048, 256, 0, stream>>>(segs);

  for (int l = 0; l < 2; l++) {
    const unsigned short* WqL = Wq16 + (size_t)l * 1048576;
    const unsigned short* WkL = Wk16 + (size_t)l * 1048576;
    const unsigned short* WvL = Wv16 + (size_t)l * 1048576;
    const unsigned short* WoL = Wo16 + (size_t)l * 1048576;
    const unsigned short* F1L = F116 + (size_t)l * 4194304;
    const unsigned short* F2L = F216 + (size_t)l * 4194304;

    // ---- xT[b][c][n] = x[b][n][c]
    transpose_kernel<<<dim3(64, 16, 4), 256, 0, stream>>>(xd, xT);

    // ---- xE[b][k][c] = sum_n E_w[k,n] * xT[b][c][n]   (pure NT, z = b)
    GemmP pe{};
    pe.A = E16; pe.sAm = 4096; pe.K = 4096;
    pe.B = xT; pe.sBn = 4096; pe.bLo = 4194304;
    pe.C = xE; pe.cLo = 262144; pe.sCm = 1024; pe.sCn = 1;
    pe.scale = 1.f; pe.cdtype = 0;
    gemm_nt<64,64,2,2><<<dim3(4, 16, 4), 256, 0, stream>>>(pe);

    // ---- EK + EVt in one launch (z<64 -> EK, z>=64 -> EVt)
    ekv_kernel<<<dim3(4, 1, 128), 256, 0, stream>>>(xE, WkL, WvL, E_b, EK, EVt);

    // ---- Q (all batches) = x @ Wq^T : [16384,1024]   (overwrites xT region)
    GemmP pq{};
    pq.A = xd; pq.sAm = 1024; pq.K = 1024;
    pq.B = WqL; pq.sBn = 1024;
    pq.C = Qb4; pq.sCm = 1024; pq.sCn = 1;
    pq.scale = 1.f; pq.cdtype = 0;
    gemm256<<<dim3(64, 4, 1), 512, 0, stream>>>(pq);

    // ---- fused attention: cat[b][n][h*64+d] overwrites Q slice in place
    attn_kernel<<<dim3(64, 1, 64), 256, 0, stream>>>(Qb4, EK, EVt);

    // ---- y = cat @ wo^T + wo_b -> bf16 ybuf (in d_out scratch)
    GemmP pw{};
    pw.A = Qb4; pw.sAm = 1024; pw.K = 1024;
    pw.B = WoL; pw.sBn = 1024;
    pw.biasN = wo_b + (size_t)l * 1024;
    pw.C = ybuf; pw.cdtype = 0;
    pw.sCm = 1024; pw.sCn = 1; pw.scale = 1.f;
    gemm256<<<dim3(64, 4, 1), 512, 0, stream>>>(pw);

    // ---- x = LN1(x + y)  (bf16 in, bf16 out)
    add_ln_kernel<<<16384, 256, 0, stream>>>(xd, ybuf, nullptr, xd, nullptr,
                                             ln1_g + (size_t)l * 1024,
                                             ln1_b + (size_t)l * 1024);

    // ---- FFN, row-chunked: h = relu(x@W1^T+b1) -> R; y = h@W2^T+b2
    for (int r0 = 0; r0 < 16384; r0 += rowc) {
      GemmP f1{};
      f1.A = xd + (size_t)r0 * 1024; f1.sAm = 1024; f1.K = 1024;
      f1.B = F1L; f1.sBn = 1024;
      f1.C = R; f1.sCm = 4096; f1.sCn = 1;
      f1.biasN = ff_b1 + (size_t)l * 4096; f1.scale = 1.f; f1.relu = 1; f1.cdtype = 0;
      gemm256<<<dim3(rowc / 256, 16, 1), 512, 0, stream>>>(f1);

      GemmP f2{};
      f2.A = (unsigned short*)R; f2.sAm = 4096; f2.K = 4096;
      f2.B = F2L; f2.sBn = 4096;
      f2.biasN = ff_b2 + (size_t)l * 1024;
      f2.sCm = 1024; f2.sCn = 1; f2.scale = 1.f;
      if (l == 1) { f2.C = xfout + (size_t)r0 * 1024; f2.cdtype = 1; }  // f32 y in d_out
      else        { f2.C = ybuf + (size_t)r0 * 1024;  f2.cdtype = 0; }
      gemm256<<<dim3(rowc / 256, 4, 1), 512, 0, stream>>>(f2);
    }
    // ---- x = LN2(x + y); final layer: y f32 in d_out, LN in-place f32 out
    if (l == 1)
      add_ln_kernel<<<16384, 256, 0, stream>>>(xd, nullptr, xfout, nullptr, xfout,
                                               ln2_g + 1024, ln2_b + 1024);
    else
      add_ln_kernel<<<16384, 256, 0, stream>>>(xd, ybuf, nullptr, xd, nullptr,
                                               ln2_g, ln2_b);
  }
}

// Round 15
// 1214.655 us; speedup vs baseline: 1.1852x; 1.0024x over previous
//
#include <hip/hip_runtime.h>
#include <hip/hip_bf16.h>

typedef __attribute__((ext_vector_type(8))) short short8;
typedef __attribute__((ext_vector_type(4))) float f32x4;

__device__ __forceinline__ unsigned short dev_f2bf(float f) {
  __hip_bfloat16 b = __float2bfloat16(f);
  union { __hip_bfloat16 b; unsigned short u; } c; c.b = b; return c.u;
}
__device__ __forceinline__ float dev_bf2f(unsigned short u) {
  union { unsigned int i; float f; } c; c.i = ((unsigned int)u) << 16; return c.f;
}

// async global->LDS, 16B per lane; dest = lds_base(wave-uniform) + lane*16
__device__ __forceinline__ void gload_lds16(const unsigned short* g, unsigned short* l) {
  __builtin_amdgcn_global_load_lds(
      (const __attribute__((address_space(1))) void*)(const void*)g,
      (__attribute__((address_space(3))) void*)(void*)l, 16, 0, 0);
}

struct GemmP {
  const unsigned short* A;   // bf16 bits
  const unsigned short* B;   // bf16 bits
  void* C;
  const float* biasN;        // bias by output col, may be null
  const float* biasM;        // bias by output row, may be null
  long long aHi, aLo, bHi, bLo, cHi, cLo;  // per-z base: (z>>4)*Hi + (z&15)*Lo
  int K;
  int sAm;                   // A row stride (k stride == 1)
  int sBn;                   // B row stride (k stride == 1)
  int sCm, sCn;
  float scale;
  int relu;
  int cdtype;                // 0=bf16, 1=f32, 3=f32 +=
};

// ---------------------------------------------------------------------------
// Big-GEMM: 256x256 tile, 512 threads (8 waves, 2Mx4N), BK=64, double-buffered
// LDS with counted vmcnt pipeline (never drains to 0 in main loop).
// LDS(row, c16) holds global(row, c16 ^ (row&7)); reads apply the same XOR.
// XCD swizzle (nwg%8==0): A-GROUPED decode. This structure is the measured
// plain-HIP ceiling for these shapes (~31% MfmaUtil; 5 schedule variants).
// ---------------------------------------------------------------------------
__global__ __launch_bounds__(512, 2) void gemm256(GemmP p) {
  __shared__ __align__(16) unsigned short lds[2][2][256 * 64];  // 128 KiB

  const int tid = threadIdx.x;
  const int lane = tid & 63;
  const int wid = tid >> 6;       // 0..7
  const int wm = wid >> 2;        // 0..1
  const int wn = wid & 3;         // 0..3

  int id = blockIdx.y * gridDim.x + blockIdx.x;
  const int nwg = gridDim.x * gridDim.y;
  if ((nwg & 7) == 0) id = (id & 7) * (nwg >> 3) + (id >> 3);
  const long long m0 = (long long)(id / gridDim.y) * 256;   // A-grouped decode
  const long long n0 = (long long)(id % gridDim.y) * 256;

  const int srow8 = lane >> 3;                 // 0..7
  const int scol = ((lane & 7) ^ srow8) * 8;   // swizzled short offset

  const long long sA64 = 64LL * p.sAm, sB64 = 64LL * p.sBn;
  const unsigned short* aBase = p.A + (m0 + wid * 8 + srow8) * (long long)p.sAm + scol;
  const unsigned short* bBase = p.B + (n0 + wid * 8 + srow8) * (long long)p.sBn + scol;

  f32x4 acc[8][4];
#pragma unroll
  for (int i = 0; i < 8; i++)
#pragma unroll
    for (int j = 0; j < 4; j++)
      acc[i][j] = f32x4{0.f, 0.f, 0.f, 0.f};

  const int nt = p.K >> 6;

  auto stage = [&](int buf, int t) {
    const long long k0 = (long long)t * 64;
#pragma unroll
    for (int h = 0; h < 4; h++)
      gload_lds16(aBase + h * sA64 + k0, &lds[buf][0][(h * 64 + wid * 8) * 64]);
#pragma unroll
    for (int h = 0; h < 4; h++)
      gload_lds16(bBase + h * sB64 + k0, &lds[buf][1][(h * 64 + wid * 8) * 64]);
  };

  stage(0, 0);
  stage(1, 1);

  for (int t = 0; t < nt; t++) {
    const int cur = t & 1;
    if (t + 1 < nt) asm volatile("s_waitcnt vmcnt(8)" ::: "memory");
    else            asm volatile("s_waitcnt vmcnt(0)" ::: "memory");
    __builtin_amdgcn_s_barrier();
    __builtin_amdgcn_sched_barrier(0);

    const unsigned short* Asb = lds[cur][0];
    const unsigned short* Bsb = lds[cur][1];
#pragma unroll
    for (int ks = 0; ks < 2; ks++) {
      const int c16 = ks * 4 + (lane >> 4);
      short8 a[8], b[4];
#pragma unroll
      for (int i = 0; i < 8; i++) {
        const int r = wm * 128 + i * 16 + (lane & 15);
        a[i] = *(const short8*)&Asb[r * 64 + ((c16 ^ (r & 7)) << 3)];
      }
#pragma unroll
      for (int j = 0; j < 4; j++) {
        const int r = wn * 64 + j * 16 + (lane & 15);
        b[j] = *(const short8*)&Bsb[r * 64 + ((c16 ^ (r & 7)) << 3)];
      }
      __builtin_amdgcn_s_setprio(1);
#pragma unroll
      for (int i = 0; i < 8; i++)
#pragma unroll
        for (int j = 0; j < 4; j++)
          acc[i][j] = __builtin_amdgcn_mfma_f32_16x16x32_bf16(a[i], b[j], acc[i][j], 0, 0, 0);
      __builtin_amdgcn_s_setprio(0);
    }
    __builtin_amdgcn_sched_barrier(0);
    __builtin_amdgcn_s_barrier();
    __builtin_amdgcn_sched_barrier(0);
    if (t + 2 < nt) stage(cur, t + 2);
  }

#pragma unroll
  for (int i = 0; i < 8; i++) {
#pragma unroll
    for (int j = 0; j < 4; j++) {
      const int col = (int)n0 + wn * 64 + j * 16 + (lane & 15);
      float bn = p.biasN ? p.biasN[col] : 0.f;
#pragma unroll
      for (int r = 0; r < 4; r++) {
        const long long row = m0 + wm * 128 + i * 16 + ((lane >> 4) << 2) + r;
        float v = acc[i][j][r] * p.scale + bn;
        if (p.relu) v = fmaxf(v, 0.f);
        const long long addr = row * p.sCm + col;
        if (p.cdtype == 0)      ((unsigned short*)p.C)[addr] = dev_f2bf(v);
        else if (p.cdtype == 3) ((float*)p.C)[addr] += v;
        else                    ((float*)p.C)[addr] = v;
      }
    }
  }
}

// ---------------------------------------------------------------------------
// Fully fused attention, QBLK=64: per block = 64 q-rows x one head z.
// LDS: u0 = [As 8KB | Bs 32KB] (Ps 32KB aliases u0 after phase 1), Vs 32KB.
// Total 73 KB -> 2 blocks/CU. Phases: QK^T -> in-reg softmax -> Ps(bf16,
// granule-XOR) -> PV -> bf16 store in place over the Q slice.
// ---------------------------------------------------------------------------
__global__ __launch_bounds__(256, 2) void attn_kernel(
    const unsigned short* __restrict__ Q, const unsigned short* __restrict__ EK,
    const unsigned short* __restrict__ EVt) {
  __shared__ __align__(16) unsigned short u0[20480];       // As(4096) + Bs(16384)
  __shared__ __align__(16) unsigned short Vs[64 * 256];    // 32 KB
  __shared__ float red[2][2][64];

  unsigned short* As = u0;           // 64 x 64
  unsigned short* Bs = u0 + 4096;    // 256 x 64
  unsigned short* Ps = u0;           // 64 x 256 (aliases As+Bs after QK phase)

  const int tid = threadIdx.x;
  const int lane = tid & 63;
  const int wid = tid >> 6;
  const int wm = wid >> 1, wn = wid & 1;   // 2x2 wave grid
  const int m0 = blockIdx.x * 64;
  const int z = blockIdx.z;
  unsigned short* Qz = (unsigned short*)Q + (long long)(z >> 4) * 4194304 + (long long)(z & 15) * 64;
  const unsigned short* EKz = EK + (long long)z * 16384;
  const unsigned short* EVz = EVt + (long long)z * 16384;

  const int srow = tid >> 3;
  const int scol = ((tid & 7) ^ (srow & 7)) * 8;

#pragma unroll
  for (int i = 0; i < 2; i++)
    gload_lds16(Qz + (long long)(m0 + i * 32 + srow) * 1024 + scol, &As[i * 2048 + wid * 512]);
#pragma unroll
  for (int i = 0; i < 8; i++)
    gload_lds16(EKz + (long long)(i * 32 + srow) * 64 + scol, &Bs[i * 2048 + wid * 512]);
  // EVt: physical granule pg holds logical granule (pg&31)^(d&7) of row d=pg>>5
#pragma unroll
  for (int c = 0; c < 8; c++) {
    const int pg = (c * 4 + wid) * 64 + lane;
    const int d = pg >> 5, gp = pg & 31;
    gload_lds16(EVz + d * 256 + ((gp ^ (d & 7)) << 3), &Vs[(c * 4 + wid) * 512]);
  }
  __syncthreads();

  f32x4 acc[2][8];
#pragma unroll
  for (int i = 0; i < 2; i++)
#pragma unroll
    for (int j = 0; j < 8; j++)
      acc[i][j] = f32x4{0.f, 0.f, 0.f, 0.f};

#pragma unroll
  for (int ks = 0; ks < 2; ks++) {
    const int c16 = ks * 4 + (lane >> 4);
    short8 a[2], b[8];
#pragma unroll
    for (int i = 0; i < 2; i++) {
      const int row = wm * 32 + i * 16 + (lane & 15);
      a[i] = *(const short8*)&As[row * 64 + ((c16 ^ (row & 7)) << 3)];
    }
#pragma unroll
    for (int j = 0; j < 8; j++) {
      const int row = wn * 128 + j * 16 + (lane & 15);
      b[j] = *(const short8*)&Bs[row * 64 + ((c16 ^ (row & 7)) << 3)];
    }
#pragma unroll
    for (int i = 0; i < 2; i++)
#pragma unroll
      for (int j = 0; j < 8; j++)
        acc[i][j] = __builtin_amdgcn_mfma_f32_16x16x32_bf16(a[i], b[j], acc[i][j], 0, 0, 0);
  }

  const int rr4 = (lane >> 4) << 2;
#pragma unroll
  for (int i = 0; i < 2; i++) {
#pragma unroll
    for (int r = 0; r < 4; r++) {
      float m = acc[i][0][r];
#pragma unroll
      for (int j = 1; j < 8; j++) m = fmaxf(m, acc[i][j][r]);
      m = fmaxf(m, __shfl_xor(m, 1));
      m = fmaxf(m, __shfl_xor(m, 2));
      m = fmaxf(m, __shfl_xor(m, 4));
      m = fmaxf(m, __shfl_xor(m, 8));
      if ((lane & 15) == 0) red[0][wn][wm * 32 + i * 16 + rr4 + r] = m;
    }
  }
  __syncthreads();
  float fm[2][4];
#pragma unroll
  for (int i = 0; i < 2; i++)
#pragma unroll
    for (int r = 0; r < 4; r++) {
      const int row = wm * 32 + i * 16 + rr4 + r;
      fm[i][r] = fmaxf(red[0][0][row], red[0][1][row]);
    }
#pragma unroll
  for (int i = 0; i < 2; i++) {
#pragma unroll
    for (int r = 0; r < 4; r++) {
      float s = 0.f;
#pragma unroll
      for (int j = 0; j < 8; j++) {
        float e = __expf((acc[i][j][r] - fm[i][r]) * 0.125f);
        acc[i][j][r] = e;
        s += e;
      }
      s += __shfl_xor(s, 1);
      s += __shfl_xor(s, 2);
      s += __shfl_xor(s, 4);
      s += __shfl_xor(s, 8);
      if ((lane & 15) == 0) red[1][wn][wm * 32 + i * 16 + rr4 + r] = s;
    }
  }
  __syncthreads();   // last As/Bs reads done; Ps may now overwrite u0
#pragma unroll
  for (int i = 0; i < 2; i++) {
#pragma unroll
    for (int r = 0; r < 4; r++) {
      const int row = wm * 32 + i * 16 + rr4 + r;
      const float inv = 1.f / (red[1][0][row] + red[1][1][row]);
#pragma unroll
      for (int j = 0; j < 8; j++) {
        const int col = wn * 128 + j * 16 + (lane & 15);
        Ps[row * 256 + (((col >> 3) ^ (row & 7)) << 3) + (col & 7)] =
            dev_f2bf(acc[i][j][r] * inv);
      }
    }
  }
  __syncthreads();

  // PV: out[q][d] = sum_k P[q,k] * EVt[d,k]; per wave 32q x 32d
  f32x4 acc2[2][2];
#pragma unroll
  for (int i = 0; i < 2; i++)
#pragma unroll
    for (int jj = 0; jj < 2; jj++)
      acc2[i][jj] = f32x4{0.f, 0.f, 0.f, 0.f};

#pragma unroll
  for (int ks = 0; ks < 8; ks++) {
    const int G = ks * 4 + (lane >> 4);
    short8 pa[2], pb[2];
#pragma unroll
    for (int i = 0; i < 2; i++) {
      const int row = wm * 32 + i * 16 + (lane & 15);
      pa[i] = *(const short8*)&Ps[row * 256 + ((G ^ (row & 7)) << 3)];
    }
#pragma unroll
    for (int jj = 0; jj < 2; jj++) {
      const int d = wn * 32 + jj * 16 + (lane & 15);
      pb[jj] = *(const short8*)&Vs[d * 256 + ((G ^ (d & 7)) << 3)];
    }
#pragma unroll
    for (int i = 0; i < 2; i++)
#pragma unroll
      for (int jj = 0; jj < 2; jj++)
        acc2[i][jj] = __builtin_amdgcn_mfma_f32_16x16x32_bf16(pa[i], pb[jj], acc2[i][jj], 0, 0, 0);
  }

#pragma unroll
  for (int i = 0; i < 2; i++) {
#pragma unroll
    for (int jj = 0; jj < 2; jj++) {
#pragma unroll
      for (int r = 0; r < 4; r++) {
        const int qrow = m0 + wm * 32 + i * 16 + rr4 + r;
        const int dcol = wn * 32 + jj * 16 + (lane & 15);
        Qz[(long long)qrow * 1024 + dcol] = dev_f2bf(acc2[i][jj][r]);
      }
    }
  }
}

// ---------------------------------------------------------------------------
// Combined EK/EVt kernel: grid (4,1,128). z<64 -> EK[zz][k][d] = xE[b]@Wk[h]^T
// + E_b[k]; z>=64 -> EVt[zz][d][k] = (xE[b]@Wv[h]^T + E_b[k])^T.
// ---------------------------------------------------------------------------
__global__ __launch_bounds__(256, 2) void ekv_kernel(
    const unsigned short* __restrict__ xE, const unsigned short* __restrict__ Wk,
    const unsigned short* __restrict__ Wv, const float* __restrict__ E_b,
    unsigned short* __restrict__ EK, unsigned short* __restrict__ EVt) {
  __shared__ __align__(16) unsigned short As[64 * 64];
  __shared__ __align__(16) unsigned short Bs[64 * 64];

  const int tid = threadIdx.x;
  const int lane = tid & 63;
  const int wid = tid >> 6;
  const int wm = wid >> 1, wn = wid & 1;
  const int z = blockIdx.z;
  const int isv = z >> 6;          // 0 = K, 1 = V
  const int zz = z & 63;
  const int b = zz >> 4, h = zz & 15;
  const int m0 = blockIdx.x * 64;

  const unsigned short* Ag = xE + (long long)b * 262144;
  const unsigned short* Bg = (isv ? Wv : Wk) + (long long)h * 65536;

  const int srow = tid >> 3;                      // 0..31
  const int scol = ((tid & 7) ^ (srow & 7)) * 8;  // swizzled 16B column

  f32x4 acc[2][2];
#pragma unroll
  for (int i = 0; i < 2; i++)
#pragma unroll
    for (int j = 0; j < 2; j++)
      acc[i][j] = f32x4{0.f, 0.f, 0.f, 0.f};

  for (int k0 = 0; k0 < 1024; k0 += 64) {
#pragma unroll
    for (int i = 0; i < 2; i++)
      gload_lds16(Ag + (long long)(m0 + i * 32 + srow) * 1024 + (k0 + scol),
                  &As[i * 2048 + wid * 512]);
#pragma unroll
    for (int i = 0; i < 2; i++)
      gload_lds16(Bg + (long long)(i * 32 + srow) * 1024 + (k0 + scol),
                  &Bs[i * 2048 + wid * 512]);
    __syncthreads();
#pragma unroll
    for (int ks = 0; ks < 2; ks++) {
      const int c16 = ks * 4 + (lane >> 4);
      short8 a[2], bfr[2];
#pragma unroll
      for (int i = 0; i < 2; i++) {
        const int row = wm * 32 + i * 16 + (lane & 15);
        a[i] = *(const short8*)&As[row * 64 + ((c16 ^ (row & 7)) << 3)];
      }
#pragma unroll
      for (int j = 0; j < 2; j++) {
        const int row = wn * 32 + j * 16 + (lane & 15);
        bfr[j] = *(const short8*)&Bs[row * 64 + ((c16 ^ (row & 7)) << 3)];
      }
#pragma unroll
      for (int i = 0; i < 2; i++)
#pragma unroll
        for (int j = 0; j < 2; j++)
          acc[i][j] = __builtin_amdgcn_mfma_f32_16x16x32_bf16(a[i], bfr[j], acc[i][j], 0, 0, 0);
    }
    __syncthreads();
  }

  const long long cb = (long long)zz * 16384;
#pragma unroll
  for (int i = 0; i < 2; i++) {
#pragma unroll
    for (int j = 0; j < 2; j++) {
      const int col = wn * 32 + j * 16 + (lane & 15);
#pragma unroll
      for (int r = 0; r < 4; r++) {
        const int row = m0 + wm * 32 + i * 16 + ((lane >> 4) << 2) + r;
        const float v = acc[i][j][r] + E_b[row];
        if (isv) EVt[cb + (long long)col * 256 + row] = dev_f2bf(v);
        else     EK[cb + (long long)row * 64 + col] = dev_f2bf(v);
      }
    }
  }
}

// General NT GEMM (small/batched shapes): C[z,m,n] = scale*sum_k A[m,k]*B[n,k]
template<int BM, int BN, int WM, int WN>
__global__ __launch_bounds__(256, 2) void gemm_nt(GemmP p) {
  constexpr int BK = 64;
  constexpr int TM = BM / WM, TN = BN / WN;
  constexpr int FM = TM / 16, FN = TN / 16;
  __shared__ __align__(16) unsigned short As[BM * BK];
  __shared__ __align__(16) unsigned short Bs[BN * BK];

  const int tid = threadIdx.x;
  const int lane = tid & 63;
  const int wid = tid >> 6;
  const int wm = wid / WN, wn = wid % WN;
  const int m0 = blockIdx.x * BM;
  const int n0 = blockIdx.y * BN;
  const int z = blockIdx.z;
  const int zq = z >> 4, zr = z & 15;
  const unsigned short* Ag = p.A + (long long)zq * p.aHi + (long long)zr * p.aLo;
  const unsigned short* Bg = p.B + (long long)zq * p.bHi + (long long)zr * p.bLo;

  const int srow = tid >> 3;                      // 0..31
  const int scol = ((tid & 7) ^ (srow & 7)) * 8;  // swizzled 16B column
  constexpr int AC = BM / 32, BC = BN / 32;

  f32x4 acc[FM][FN];
#pragma unroll
  for (int i = 0; i < FM; i++)
#pragma unroll
    for (int j = 0; j < FN; j++)
      acc[i][j] = f32x4{0.f, 0.f, 0.f, 0.f};

  for (int k0 = 0; k0 < p.K; k0 += BK) {
#pragma unroll
    for (int i = 0; i < AC; i++)
      gload_lds16(Ag + (long long)(m0 + i * 32 + srow) * p.sAm + (k0 + scol),
                  &As[i * 2048 + wid * 512]);
#pragma unroll
    for (int i = 0; i < BC; i++)
      gload_lds16(Bg + (long long)(n0 + i * 32 + srow) * p.sBn + (k0 + scol),
                  &Bs[i * 2048 + wid * 512]);
    __syncthreads();
#pragma unroll
    for (int ks = 0; ks < 2; ks++) {
      const int c16 = ks * 4 + (lane >> 4);
      short8 a[FM], b[FN];
#pragma unroll
      for (int i = 0; i < FM; i++) {
        const int row = wm * TM + i * 16 + (lane & 15);
        a[i] = *(const short8*)&As[row * 64 + ((c16 ^ (row & 7)) << 3)];
      }
#pragma unroll
      for (int j = 0; j < FN; j++) {
        const int row = wn * TN + j * 16 + (lane & 15);
        b[j] = *(const short8*)&Bs[row * 64 + ((c16 ^ (row & 7)) << 3)];
      }
#pragma unroll
      for (int i = 0; i < FM; i++)
#pragma unroll
        for (int j = 0; j < FN; j++)
          acc[i][j] = __builtin_amdgcn_mfma_f32_16x16x32_bf16(a[i], b[j], acc[i][j], 0, 0, 0);
    }
    __syncthreads();
  }

  const long long zc_ = (long long)zq * p.cHi + (long long)zr * p.cLo;
#pragma unroll
  for (int i = 0; i < FM; i++) {
#pragma unroll
    for (int j = 0; j < FN; j++) {
      const int col = n0 + wn * TN + j * 16 + (lane & 15);
      float bn = p.biasN ? p.biasN[col] : 0.f;
#pragma unroll
      for (int r = 0; r < 4; r++) {
        const int row = m0 + wm * TM + i * 16 + ((lane >> 4) << 2) + r;
        float v = acc[i][j][r] * p.scale + bn;
        if (p.biasM) v += p.biasM[row];
        if (p.relu) v = fmaxf(v, 0.f);
        const long long addr = zc_ + (long long)row * p.sCm + (long long)col * p.sCn;
        if (p.cdtype == 0)      ((unsigned short*)p.C)[addr] = dev_f2bf(v);
        else if (p.cdtype == 3) ((float*)p.C)[addr] += v;
        else                    ((float*)p.C)[addr] = v;
      }
    }
  }
}

// fused x-ingest: f32 x 64x64 tile -> xd (bf16, straight) + xT (bf16, transposed)
__global__ __launch_bounds__(256) void ingest_kernel(const float* __restrict__ in,
    unsigned short* __restrict__ xd, unsigned short* __restrict__ xT) {
  __shared__ unsigned short t[64][72];
  const int b = blockIdx.z;
  const int n0 = blockIdx.x * 64, c0 = blockIdx.y * 64;
  const int r = threadIdx.x >> 2;          // 0..63
  const int cc = (threadIdx.x & 3) * 16;   // 0,16,32,48
  const size_t base = (size_t)b * 4194304 + (size_t)(n0 + r) * 1024 + c0 + cc;
  const float4* ip4 = (const float4*)(in + base);
  float4 a0 = ip4[0], a1 = ip4[1], a2 = ip4[2], a3 = ip4[3];
  short8 v0, v1;
  v0[0] = (short)dev_f2bf(a0.x); v0[1] = (short)dev_f2bf(a0.y);
  v0[2] = (short)dev_f2bf(a0.z); v0[3] = (short)dev_f2bf(a0.w);
  v0[4] = (short)dev_f2bf(a1.x); v0[5] = (short)dev_f2bf(a1.y);
  v0[6] = (short)dev_f2bf(a1.z); v0[7] = (short)dev_f2bf(a1.w);
  v1[0] = (short)dev_f2bf(a2.x); v1[1] = (short)dev_f2bf(a2.y);
  v1[2] = (short)dev_f2bf(a2.z); v1[3] = (short)dev_f2bf(a2.w);
  v1[4] = (short)dev_f2bf(a3.x); v1[5] = (short)dev_f2bf(a3.y);
  v1[6] = (short)dev_f2bf(a3.z); v1[7] = (short)dev_f2bf(a3.w);
  *(short8*)&t[r][cc] = v0;
  *(short8*)&t[r][cc + 8] = v1;
  *(short8*)(xd + base) = v0;
  *(short8*)(xd + base + 8) = v1;
  __syncthreads();
  unsigned short* op = xT + (size_t)b * 4194304 + (size_t)c0 * 4096 + n0;
  short8 w0, w1;
#pragma unroll
  for (int j = 0; j < 8; j++) {
    w0[j] = (short)t[cc + j][r];
    w1[j] = (short)t[cc + 8 + j][r];
  }
  *(short8*)(op + (size_t)r * 4096 + cc)     = w0;
  *(short8*)(op + (size_t)r * 4096 + cc + 8) = w1;
}

// 64x64 tiled transpose: in [b][4096][1024] -> out [b][1024][4096] (bf16)
__global__ __launch_bounds__(256) void transpose_kernel(const unsigned short* __restrict__ in,
                                                        unsigned short* __restrict__ out) {
  __shared__ unsigned short t[64][72];
  const int b = blockIdx.z;
  const int n0 = blockIdx.x * 64, c0 = blockIdx.y * 64;
  const int r = threadIdx.x >> 2;          // 0..63
  const int cc = (threadIdx.x & 3) * 16;   // 0,16,32,48
  const unsigned short* ip = in + (size_t)b * 4194304 + (size_t)n0 * 1024 + c0;
  *(short8*)&t[r][cc]     = *(const short8*)(ip + (size_t)r * 1024 + cc);
  *(short8*)&t[r][cc + 8] = *(const short8*)(ip + (size_t)r * 1024 + cc + 8);
  __syncthreads();
  unsigned short* op = out + (size_t)b * 4194304 + (size_t)c0 * 4096 + n0;
  short8 w0, w1;
#pragma unroll
  for (int j = 0; j < 8; j++) {
    w0[j] = (short)t[cc + j][r];
    w1[j] = (short)t[cc + 8 + j][r];
  }
  *(short8*)(op + (size_t)r * 4096 + cc)     = w0;
  *(short8*)(op + (size_t)r * 4096 + cc + 8) = w1;
}

// segmented f32 -> bf16 convert: 7 weight segments in one launch
struct CvtSegs {
  const float* src[7];
  unsigned short* dst[7];
  long long n4[7];
};
__global__ void cvt_all_kernel(CvtSegs s) {
  const long long stride = (long long)gridDim.x * blockDim.x;
#pragma unroll
  for (int seg = 0; seg < 7; seg++) {
    const float4* sp = (const float4*)s.src[seg];
    ushort4* dp = (ushort4*)s.dst[seg];
    const long long n4 = s.n4[seg];
    for (long long i = (long long)blockIdx.x * blockDim.x + threadIdx.x; i < n4; i += stride) {
      float4 v = sp[i];
      ushort4 u;
      u.x = dev_f2bf(v.x); u.y = dev_f2bf(v.y); u.z = dev_f2bf(v.z); u.w = dev_f2bf(v.w);
      dp[i] = u;
    }
  }
}

// LN over rows of 1024: t = bf2f(xr) + y, where y = yf[row] (f32) if yf else
// bf2f(yr[row]). Writes bf16 LN(t) to xw (if non-null) and f32 LN(t) to fout
// (if non-null). fout may alias yf (per-row read-then-write, block-local).
__global__ __launch_bounds__(256) void add_ln_kernel(
    const unsigned short* __restrict__ xr, const unsigned short* __restrict__ yr,
    const float* __restrict__ yf,
    unsigned short* __restrict__ xw, float* __restrict__ fout,
    const float* __restrict__ g, const float* __restrict__ b) {
  const long long row = blockIdx.x;
  const int tid = threadIdx.x;
  ushort4 xv = ((const ushort4*)(xr + row * 1024))[tid];
  float4 t;
  if (yf) {
    float4 yv = ((const float4*)(yf + row * 1024))[tid];
    t = float4{dev_bf2f(xv.x) + yv.x, dev_bf2f(xv.y) + yv.y,
               dev_bf2f(xv.z) + yv.z, dev_bf2f(xv.w) + yv.w};
  } else {
    ushort4 yv = ((const ushort4*)(yr + row * 1024))[tid];
    t = float4{dev_bf2f(xv.x) + dev_bf2f(yv.x), dev_bf2f(xv.y) + dev_bf2f(yv.y),
               dev_bf2f(xv.z) + dev_bf2f(yv.z), dev_bf2f(xv.w) + dev_bf2f(yv.w)};
  }
  float s = t.x + t.y + t.z + t.w;
  float ss = t.x * t.x + t.y * t.y + t.z * t.z + t.w * t.w;
#pragma unroll
  for (int off = 32; off > 0; off >>= 1) { s += __shfl_xor(s, off); ss += __shfl_xor(ss, off); }
  __shared__ float sm[8];
  const int wid = tid >> 6, lane = tid & 63;
  if (lane == 0) { sm[wid] = s; sm[4 + wid] = ss; }
  __syncthreads();
  s = sm[0] + sm[1] + sm[2] + sm[3];
  ss = sm[4] + sm[5] + sm[6] + sm[7];
  const float mean = s * (1.f / 1024.f);
  const float var = ss * (1.f / 1024.f) - mean * mean;
  const float rs = rsqrtf(var + 1e-5f);
  float4 gv = ((const float4*)g)[tid];
  float4 bv = ((const float4*)b)[tid];
  float4 o = {(t.x - mean) * rs * gv.x + bv.x, (t.y - mean) * rs * gv.y + bv.y,
              (t.z - mean) * rs * gv.z + bv.z, (t.w - mean) * rs * gv.w + bv.w};
  if (xw) {
    ushort4 ob;
    ob.x = dev_f2bf(o.x); ob.y = dev_f2bf(o.y); ob.z = dev_f2bf(o.z); ob.w = dev_f2bf(o.w);
    ((ushort4*)(xw + row * 1024))[tid] = ob;
  }
  if (fout) ((float4*)(fout + row * 1024))[tid] = o;
}

// canary: unambiguous "workspace too small" signal (absmax ~ 100+max|ref|)
__global__ void fill_canary_kernel(float* p, long long n) {
  long long i = (long long)blockIdx.x * blockDim.x + threadIdx.x;
  const long long stride = (long long)gridDim.x * blockDim.x;
  for (; i < n; i += stride) p[i] = 100.0f;
}

extern "C" void kernel_launch(void* const* d_in, const int* in_sizes, int n_in,
                              void* d_out, int out_size, void* d_ws, size_t ws_size,
                              hipStream_t stream) {
  const float* x_in  = (const float*)d_in[0];
  const float* E_w   = (const float*)d_in[1];
  const float* E_b   = (const float*)d_in[2];
  const float* Wq    = (const float*)d_in[3];
  const float* Wk    = (const float*)d_in[4];
  const float* Wv    = (const float*)d_in[5];
  const float* wo_w  = (const float*)d_in[6];
  const float* wo_b  = (const float*)d_in[7];
  const float* ln1_g = (const float*)d_in[8];
  const float* ln1_b = (const float*)d_in[9];
  const float* ff_w1 = (const float*)d_in[10];
  const float* ff_b1 = (const float*)d_in[11];
  const float* ff_w2 = (const float*)d_in[12];
  const float* ff_b2 = (const float*)d_in[13];
  const float* ln2_g = (const float*)d_in[14];
  const float* ln2_b = (const float*)d_in[15];

  float* xfout = (float*)d_out;                   // final f32 output
  unsigned short* ybuf = (unsigned short*)d_out;  // bf16 y scratch (first 32 MiB of d_out)

  char* ws = (char*)d_ws;
  size_t off = 0;
  auto alloc = [&](size_t bytes) -> char* {
    char* p = ws + off;
    off = (off + bytes + 255) & ~(size_t)255;
    return p;
  };
  unsigned short* E16 = (unsigned short*)alloc(1048576ULL * 2);  // E_w bf16 [256,4096]
  unsigned short* Wq16 = (unsigned short*)alloc(2097152ULL * 2); // both layers
  unsigned short* Wk16 = (unsigned short*)alloc(2097152ULL * 2);
  unsigned short* Wv16 = (unsigned short*)alloc(2097152ULL * 2);
  unsigned short* Wo16 = (unsigned short*)alloc(2097152ULL * 2);
  unsigned short* F116 = (unsigned short*)alloc(8388608ULL * 2);
  unsigned short* F216 = (unsigned short*)alloc(8388608ULL * 2);
  unsigned short* xE  = (unsigned short*)alloc(1048576ULL * 2);  // [b][256][1024]
  unsigned short* EK  = (unsigned short*)alloc(1048576ULL * 2);  // [z][256][64]
  unsigned short* EVt = (unsigned short*)alloc(1048576ULL * 2);  // [z][64][256]
  unsigned short* xd  = (unsigned short*)alloc(16777216ULL * 2); // bf16 residual x
  unsigned short* xT  = (unsigned short*)alloc(16777216ULL * 2); // x^T; later Q/cat
  unsigned short* Qb4 = xT;   // alias: xT dead once pe is done; Q/cat [16384][1024]

  size_t rem = (ws_size > off) ? ws_size - off : 0;
  size_t Rbytes = rem > 512 ? rem - 512 : 0;
  if (Rbytes > 134217728ULL) Rbytes = 134217728ULL;
  int rowc = 16384;
  while (rowc > 256 && (size_t)rowc * 8192ULL > Rbytes) rowc >>= 1;
  if ((size_t)rowc * 8192ULL > Rbytes) {
    fill_canary_kernel<<<2048, 256, 0, stream>>>(xfout, (long long)out_size);
    return;
  }
  char* R = alloc(Rbytes);   // h buffer region

  // ---- fused x ingest: xd (bf16) + xT (layer-0 transposed) in one pass
  ingest_kernel<<<dim3(64, 16, 4), 256, 0, stream>>>(x_in, xd, xT);

  // ---- weight conversions in one launch
  CvtSegs segs;
  segs.src[0] = E_w;   segs.dst[0] = E16;  segs.n4[0] = 1048576 / 4;
  segs.src[1] = Wq;    segs.dst[1] = Wq16; segs.n4[1] = 2097152 / 4;
  segs.src[2] = Wk;    segs.dst[2] = Wk16; segs.n4[2] = 2097152 / 4;
  segs.src[3] = Wv;    segs.dst[3] = Wv16; segs.n4[3] = 2097152 / 4;
  segs.src[4] = wo_w;  segs.dst[4] = Wo16; segs.n4[4] = 2097152 / 4;
  segs.src[5] = ff_w1; segs.dst[5] = F116; segs.n4[5] = 8388608 / 4;
  segs.src[6] = ff_w2; segs.dst[6] = F216; segs.n4[6] = 8388608 / 4;
  cvt_all_kernel<<<2048, 256, 0, stream>>>(segs);

  for (int l = 0; l < 2; l++) {
    const unsigned short* WqL = Wq16 + (size_t)l * 1048576;
    const unsigned short* WkL = Wk16 + (size_t)l * 1048576;
    const unsigned short* WvL = Wv16 + (size_t)l * 1048576;
    const unsigned short* WoL = Wo16 + (size_t)l * 1048576;
    const unsigned short* F1L = F116 + (size_t)l * 4194304;
    const unsigned short* F2L = F216 + (size_t)l * 4194304;

    // ---- xT[b][c][n] = x[b][n][c]  (layer 0: already produced by ingest)
    if (l)
      transpose_kernel<<<dim3(64, 16, 4), 256, 0, stream>>>(xd, xT);

    // ---- xE[b][k][c] = sum_n E_w[k,n] * xT[b][c][n]   (pure NT, z = b)
    GemmP pe{};
    pe.A = E16; pe.sAm = 4096; pe.K = 4096;
    pe.B = xT; pe.sBn = 4096; pe.bLo = 4194304;
    pe.C = xE; pe.cLo = 262144; pe.sCm = 1024; pe.sCn = 1;
    pe.scale = 1.f; pe.cdtype = 0;
    gemm_nt<64,64,2,2><<<dim3(4, 16, 4), 256, 0, stream>>>(pe);

    // ---- EK + EVt in one launch (z<64 -> EK, z>=64 -> EVt)
    ekv_kernel<<<dim3(4, 1, 128), 256, 0, stream>>>(xE, WkL, WvL, E_b, EK, EVt);

    // ---- Q (all batches) = x @ Wq^T : [16384,1024]   (overwrites xT region)
    GemmP pq{};
    pq.A = xd; pq.sAm = 1024; pq.K = 1024;
    pq.B = WqL; pq.sBn = 1024;
    pq.C = Qb4; pq.sCm = 1024; pq.sCn = 1;
    pq.scale = 1.f; pq.cdtype = 0;
    gemm256<<<dim3(64, 4, 1), 512, 0, stream>>>(pq);

    // ---- fused attention: cat[b][n][h*64+d] overwrites Q slice in place
    attn_kernel<<<dim3(64, 1, 64), 256, 0, stream>>>(Qb4, EK, EVt);

    // ---- y = cat @ wo^T + wo_b -> bf16 ybuf (in d_out scratch)
    GemmP pw{};
    pw.A = Qb4; pw.sAm = 1024; pw.K = 1024;
    pw.B = WoL; pw.sBn = 1024;
    pw.biasN = wo_b + (size_t)l * 1024;
    pw.C = ybuf; pw.cdtype = 0;
    pw.sCm = 1024; pw.sCn = 1; pw.scale = 1.f;
    gemm256<<<dim3(64, 4, 1), 512, 0, stream>>>(pw);

    // ---- x = LN1(x + y)  (bf16 in, bf16 out)
    add_ln_kernel<<<16384, 256, 0, stream>>>(xd, ybuf, nullptr, xd, nullptr,
                                             ln1_g + (size_t)l * 1024,
                                             ln1_b + (size_t)l * 1024);

    // ---- FFN, row-chunked: h = relu(x@W1^T+b1) -> R; y = h@W2^T+b2
    for (int r0 = 0; r0 < 16384; r0 += rowc) {
      GemmP f1{};
      f1.A = xd + (size_t)r0 * 1024; f1.sAm = 1024; f1.K = 1024;
      f1.B = F1L; f1.sBn = 1024;
      f1.C = R; f1.sCm = 4096; f1.sCn = 1;
      f1.biasN = ff_b1 + (size_t)l * 4096; f1.scale = 1.f; f1.relu = 1; f1.cdtype = 0;
      gemm256<<<dim3(rowc / 256, 16, 1), 512, 0, stream>>>(f1);

      GemmP f2{};
      f2.A = (unsigned short*)R; f2.sAm = 4096; f2.K = 4096;
      f2.B = F2L; f2.sBn = 4096;
      f2.biasN = ff_b2 + (size_t)l * 1024;
      f2.sCm = 1024; f2.sCn = 1; f2.scale = 1.f;
      if (l == 1) { f2.C = xfout + (size_t)r0 * 1024; f2.cdtype = 1; }  // f32 y in d_out
      else        { f2.C = ybuf + (size_t)r0 * 1024;  f2.cdtype = 0; }
      gemm256<<<dim3(rowc / 256, 4, 1), 512, 0, stream>>>(f2);
    }
    // ---- x = LN2(x + y); final layer: y f32 in d_out, LN in-place f32 out
    if (l == 1)
      add_ln_kernel<<<16384, 256, 0, stream>>>(xd, nullptr, xfout, nullptr, xfout,
                                               ln2_g + 1024, ln2_b + 1024);
    else
      add_ln_kernel<<<16384, 256, 0, stream>>>(xd, ybuf, nullptr, xd, nullptr,
                                               ln2_g, ln2_b);
  }
}